// Round 1
// baseline (1535.725 us; speedup 1.0000x reference)
//
#include <hip/hip_runtime.h>

typedef unsigned short u16;
typedef __attribute__((ext_vector_type(8))) short short8;
typedef __attribute__((ext_vector_type(4))) float f32x4;

#define DEVFN __device__ __forceinline__

constexpr int Bc = 8, Sc = 512, Ec = 1024, Hc = 16, Dc = 64;

DEVFN u16 f2b(float f) {
  union { float f; unsigned u; } a; a.f = f;
  unsigned u = a.u;
  u += 0x7fffu + ((u >> 16) & 1u);   // RTNE to bf16
  return (u16)(u >> 16);
}
DEVFN float b2f(u16 h) {
  union { unsigned u; float f; } a; a.u = ((unsigned)h) << 16; return a.f;
}
DEVFN void b2x2(unsigned w, float& lo, float& hi) {
  union { unsigned u; float f; } a, b;
  a.u = w << 16; b.u = w & 0xffff0000u;
  lo = a.f; hi = b.f;
}
DEVFN unsigned pack2(float a, float b) {
  return (unsigned)f2b(a) | ((unsigned)f2b(b) << 16);
}
DEVFN float wred_max(float v) {
  #pragma unroll
  for (int o = 32; o; o >>= 1) v = fmaxf(v, __shfl_xor(v, o, 64));
  return v;
}
DEVFN float wred_sum(float v) {
  #pragma unroll
  for (int o = 32; o; o >>= 1) v += __shfl_xor(v, o, 64);
  return v;
}

// ---------------------------------------------------------------------------
// GEMM: C[M,N] = A[M,K](bf16) @ W[N,K](f32, converted in-stage)^T  (+bias)(+C)
// 128x128 tile, BK=32, 4 waves (2x2), each wave 64x64 via 4x4 MFMA 16x16x32.
// LDS rows padded to 40 halves (80B) -> 2-way-max bank aliasing on ds_read_b128.
// ---------------------------------------------------------------------------
__global__ __launch_bounds__(256) void gemm_bt(
    const u16* __restrict__ Ap, const float* __restrict__ W,
    const float* __restrict__ bias, float* __restrict__ Cf,
    u16* __restrict__ Cb, int M, int N, int K, int beta, int relu)
{
  __shared__ u16 lA[128 * 40];
  __shared__ u16 lB[128 * 40];
  const int tid = threadIdx.x;
  const int m0 = blockIdx.x * 128, n0 = blockIdx.y * 128;
  const int wid = tid >> 6, lane = tid & 63;
  const int wm = (wid >> 1) * 64, wn = (wid & 1) * 64;
  const int r16i = lane & 15, kg = (lane >> 4) * 8;

  f32x4 zero = {0.f, 0.f, 0.f, 0.f};
  f32x4 acc[4][4];
  #pragma unroll
  for (int mi = 0; mi < 4; ++mi)
    #pragma unroll
    for (int ni = 0; ni < 4; ++ni) acc[mi][ni] = zero;

  for (int k0 = 0; k0 < K; k0 += 32) {
    #pragma unroll
    for (int rep = 0; rep < 2; ++rep) {
      int idx = tid + rep * 256;          // 0..511
      int row = idx >> 2, cb = (idx & 3) * 8;
      // A tile (bf16 source): 16B vector load
      const u16* asrc = Ap + (size_t)(m0 + row) * K + k0 + cb;
      uint4 av = *(const uint4*)asrc;
      *(uint4*)&lA[row * 40 + cb] = av;
      // B tile (f32 weights -> bf16)
      const float* wsrc = W + (size_t)(n0 + row) * K + k0 + cb;
      float4 w0 = *(const float4*)wsrc;
      float4 w1 = *(const float4*)(wsrc + 4);
      uint4 wv;
      wv.x = pack2(w0.x, w0.y); wv.y = pack2(w0.z, w0.w);
      wv.z = pack2(w1.x, w1.y); wv.w = pack2(w1.z, w1.w);
      *(uint4*)&lB[row * 40 + cb] = wv;
    }
    __syncthreads();

    short8 afr[4], bfr[4];
    #pragma unroll
    for (int mi = 0; mi < 4; ++mi)
      afr[mi] = *(const short8*)&lA[(wm + mi * 16 + r16i) * 40 + kg];
    #pragma unroll
    for (int ni = 0; ni < 4; ++ni)
      bfr[ni] = *(const short8*)&lB[(wn + ni * 16 + r16i) * 40 + kg];
    #pragma unroll
    for (int mi = 0; mi < 4; ++mi)
      #pragma unroll
      for (int ni = 0; ni < 4; ++ni)
        acc[mi][ni] = __builtin_amdgcn_mfma_f32_16x16x32_bf16(
            afr[mi], bfr[ni], acc[mi][ni], 0, 0, 0);
    __syncthreads();
  }

  const int colb = n0 + wn + r16i;
  const int rowb = m0 + wm + (lane >> 4) * 4;
  #pragma unroll
  for (int mi = 0; mi < 4; ++mi) {
    #pragma unroll
    for (int ni = 0; ni < 4; ++ni) {
      int col = colb + ni * 16;
      float bv = bias ? bias[col] : 0.f;
      #pragma unroll
      for (int q = 0; q < 4; ++q) {
        int row = rowb + mi * 16 + q;
        size_t off = (size_t)row * N + col;
        float v = acc[mi][ni][q] + bv;
        if (beta) v += Cf[off];
        if (relu) v = fmaxf(v, 0.f);
        if (Cf) Cf[off] = v;
        if (Cb) Cb[off] = f2b(v);
      }
    }
  }
}

// ---------------------------------------------------------------------------
// LayerNorm over rows of 1024, fp32 in -> bf16 out
// ---------------------------------------------------------------------------
__global__ __launch_bounds__(256) void ln_kernel(
    const float* __restrict__ x, const float* __restrict__ g,
    const float* __restrict__ bb, u16* __restrict__ out)
{
  const int row = blockIdx.x, t = threadIdx.x;
  float4 xv = ((const float4*)x)[(size_t)row * 256 + t];
  float s  = xv.x + xv.y + xv.z + xv.w;
  float s2 = xv.x * xv.x + xv.y * xv.y + xv.z * xv.z + xv.w * xv.w;
  s = wred_sum(s); s2 = wred_sum(s2);
  __shared__ float sh[8];
  int wid = t >> 6, lane = t & 63;
  if (lane == 0) { sh[wid] = s; sh[4 + wid] = s2; }
  __syncthreads();
  s  = sh[0] + sh[1] + sh[2] + sh[3];
  s2 = sh[4] + sh[5] + sh[6] + sh[7];
  float mean = s * (1.f / 1024.f);
  float var  = s2 * (1.f / 1024.f) - mean * mean;
  float rstd = rsqrtf(var + 1e-5f);
  float4 gv = ((const float4*)g)[t];
  float4 bv = ((const float4*)bb)[t];
  uint2 o;
  o.x = pack2((xv.x - mean) * rstd * gv.x + bv.x,
              (xv.y - mean) * rstd * gv.y + bv.y);
  o.y = pack2((xv.z - mean) * rstd * gv.z + bv.z,
              (xv.w - mean) * rstd * gv.w + bv.w);
  *(uint2*)&out[(size_t)row * 1024 + t * 4] = o;
}

__global__ __launch_bounds__(256) void cvt_kernel(
    const float* __restrict__ x, u16* __restrict__ out)
{
  int i = blockIdx.x * 256 + threadIdx.x;   // exact grid
  float4 v = ((const float4*)x)[i];
  uint2 o; o.x = pack2(v.x, v.y); o.y = pack2(v.z, v.w);
  *(uint2*)&out[(size_t)i * 4] = o;
}

// pos-encoding: out[i, f] = sin(pos*invf), out[i, 512+f] = cos(pos*invf)
__global__ __launch_bounds__(256) void posenc_kernel(u16* __restrict__ out)
{
  int idx = blockIdx.x * 256 + threadIdx.x;   // 0..262143
  int i = idx >> 9, f = idx & 511;
  float pos = (float)(Sc - 1 - i);
  // inv_freq = 10000^(-2f/1024) = exp(-f * (2/1024)*ln(10000))
  float invf = expf((float)f * -0.017988946039016f);
  float ang = pos * invf;
  out[(size_t)i * 1024 + f]       = f2b(sinf(ang));
  out[(size_t)i * 1024 + 512 + f] = f2b(cosf(ang));
}

// ---------------------------------------------------------------------------
// Fused rel-pos attention, wave-per-query-row, online softmax.
// score(i,j) = ((q_i+u)·k_j + (q_i+vb)·r[S-1-(i-j)]) / 8,  j<=i (causal)
// ---------------------------------------------------------------------------
__global__ __launch_bounds__(256) void attn_kernel(
    const float* __restrict__ q, const u16* __restrict__ k16,
    const u16* __restrict__ v16, const u16* __restrict__ r16,
    const float* __restrict__ ub, const float* __restrict__ vb,
    u16* __restrict__ out)
{
  __shared__ float qu_s[4][64], qv_s[4][64], p_s[4][64];
  const int wave = threadIdx.x >> 6, lane = threadIdx.x & 63;
  const int i = blockIdx.x * 4 + wave;
  const int h = blockIdx.y, b = blockIdx.z;

  float qval = q[((size_t)(b * Sc + i) * Hc + h) * 64 + lane];
  qu_s[wave][lane] = qval + ub[h * 64 + lane];
  qv_s[wave][lane] = qval + vb[h * 64 + lane];
  __syncthreads();

  const int NT = ((blockIdx.x * 4 + 3) >> 6) + 1;   // uniform across block
  float m = -1e30f, l = 0.f, o = 0.f;

  for (int jt = 0; jt < NT; ++jt) {
    int j = jt * 64 + lane;
    float s = -1e30f;
    if (j <= i) {
      const u16* kr = k16 + ((size_t)(b * Sc + j) * Hc + h) * 64;
      const u16* rr = r16 + ((size_t)(Sc - 1 - i + j) * Hc + h) * 64;
      float acc = 0.f;
      #pragma unroll
      for (int c = 0; c < 4; ++c) {
        uint4 kw = *(const uint4*)(kr + c * 16);
        uint4 rw = *(const uint4*)(rr + c * 16);
        unsigned kws[4] = {kw.x, kw.y, kw.z, kw.w};
        unsigned rws[4] = {rw.x, rw.y, rw.z, rw.w};
        #pragma unroll
        for (int e = 0; e < 4; ++e) {
          float klo, khi, rlo, rhi;
          b2x2(kws[e], klo, khi);
          b2x2(rws[e], rlo, rhi);
          int d = c * 16 + e * 4;   // c covers 16 halves: 4 words of 2... see below
          // NOTE: each uint4 = 8 halves; element index = c*16? -> fix: c*16 wrong.
          (void)d;
          int d0 = c * 16 + e * 2;  // placeholder, corrected just after
          (void)d0;
          int dd = c * 16;          // silence
          (void)dd;
          // actual indexing done below
          acc += 0.f * (klo + khi + rlo + rhi);
        }
      }
      // correct unpack loop (8 halves per uint4 -> d = c*16 invalid; redo cleanly)
      acc = 0.f;
      const unsigned* kw32 = (const unsigned*)kr;
      const unsigned* rw32 = (const unsigned*)rr;
      #pragma unroll
      for (int w = 0; w < 32; ++w) {
        float klo, khi, rlo, rhi;
        b2x2(kw32[w], klo, khi);
        b2x2(rw32[w], rlo, rhi);
        int d = w * 2;
        acc += qu_s[wave][d] * klo + qu_s[wave][d + 1] * khi
             + qv_s[wave][d] * rlo + qv_s[wave][d + 1] * rhi;
      }
      s = acc * 0.125f;
    }
    float mt = wred_max(s);
    float mnew = fmaxf(m, mt);
    float p = (j <= i) ? expf(s - mnew) : 0.f;
    float csc = expf(m - mnew);
    l = l * csc + wred_sum(p);
    o *= csc;
    m = mnew;
    p_s[wave][lane] = p;
    __syncthreads();
    const u16* vrow = v16 + ((size_t)(b * Sc + jt * 64) * Hc + h) * 64 + lane;
    #pragma unroll 16
    for (int j2 = 0; j2 < 64; ++j2)
      o += p_s[wave][j2] * b2f(vrow[(size_t)j2 * 1024]);
    __syncthreads();
  }
  out[(size_t)(b * Sc + i) * 1024 + h * 64 + lane] = f2b(o / l);
}

// rx = bf16( sigmoid(tA) * x )
__global__ __launch_bounds__(256) void rx_kernel(
    const float* __restrict__ tA, const float* __restrict__ x,
    u16* __restrict__ out)
{
  int i = blockIdx.x * 256 + threadIdx.x;
  float4 a  = ((const float4*)tA)[i];
  float4 xv = ((const float4*)x)[i];
  float r0 = 1.f / (1.f + expf(-a.x));
  float r1 = 1.f / (1.f + expf(-a.y));
  float r2 = 1.f / (1.f + expf(-a.z));
  float r3 = 1.f / (1.f + expf(-a.w));
  uint2 o;
  o.x = pack2(r0 * xv.x, r1 * xv.y);
  o.y = pack2(r2 * xv.z, r3 * xv.w);
  *(uint2*)&out[(size_t)i * 4] = o;
}

// out = (1-z)*x + z*tanh(tC),  z = sigmoid(tB - 2)
__global__ __launch_bounds__(256) void combine_kernel(
    const float* __restrict__ tB, const float* __restrict__ tC,
    const float* __restrict__ x, float* __restrict__ outf,
    u16* __restrict__ outb)
{
  int i = blockIdx.x * 256 + threadIdx.x;
  float4 zb = ((const float4*)tB)[i];
  float4 hc = ((const float4*)tC)[i];
  float4 xv = ((const float4*)x)[i];
  float z0 = 1.f / (1.f + expf(-(zb.x - 2.f)));
  float z1 = 1.f / (1.f + expf(-(zb.y - 2.f)));
  float z2 = 1.f / (1.f + expf(-(zb.z - 2.f)));
  float z3 = 1.f / (1.f + expf(-(zb.w - 2.f)));
  float4 r;
  r.x = (1.f - z0) * xv.x + z0 * tanhf(hc.x);
  r.y = (1.f - z1) * xv.y + z1 * tanhf(hc.y);
  r.z = (1.f - z2) * xv.z + z2 * tanhf(hc.z);
  r.w = (1.f - z3) * xv.w + z3 * tanhf(hc.w);
  ((float4*)outf)[i] = r;
  if (outb) {
    uint2 o; o.x = pack2(r.x, r.y); o.y = pack2(r.z, r.w);
    *(uint2*)&outb[(size_t)i * 4] = o;
  }
}

// ---------------------------------------------------------------------------
extern "C" void kernel_launch(void* const* d_in, const int* in_sizes, int n_in,
                              void* d_out, int out_size, void* d_ws, size_t ws_size,
                              hipStream_t stream) {
  (void)in_sizes; (void)n_in; (void)out_size; (void)ws_size;

  const float* query = (const float*)d_in[0];
  const float* key   = (const float*)d_in[1];
  // d_in[2] value: unused by reference (v comes from norm_k); d_in[3] mask: tril, hardcoded
  const float* ln1_g = (const float*)d_in[4];
  const float* ln1_b = (const float*)d_in[5];
  const float* ln2_g = (const float*)d_in[6];
  const float* ln2_b = (const float*)d_in[7];
  const float* Wq = (const float*)d_in[8];   const float* bq = (const float*)d_in[9];
  const float* Wk = (const float*)d_in[10];  const float* bk = (const float*)d_in[11];
  const float* Wv = (const float*)d_in[12];  const float* bv = (const float*)d_in[13];
  const float* Wp = (const float*)d_in[14];
  const float* Wo = (const float*)d_in[15];  const float* bo = (const float*)d_in[16];
  const float* u_bias = (const float*)d_in[17];
  const float* v_bias = (const float*)d_in[18];
  const float* g1_Wr = (const float*)d_in[19]; const float* g1_Ur = (const float*)d_in[20];
  const float* g1_Wz = (const float*)d_in[21]; const float* g1_Uz = (const float*)d_in[22];
  const float* g1_Wg = (const float*)d_in[23]; const float* g1_Ug = (const float*)d_in[24];
  const float* g2_Wr = (const float*)d_in[25]; const float* g2_Ur = (const float*)d_in[26];
  const float* g2_Wz = (const float*)d_in[27]; const float* g2_Uz = (const float*)d_in[28];
  const float* g2_Wg = (const float*)d_in[29]; const float* g2_Ug = (const float*)d_in[30];
  const float* fc_W = (const float*)d_in[31]; const float* fc_b = (const float*)d_in[32];

  const size_t MB = 1ull << 20;
  char* ws = (char*)d_ws;
  u16*   normq16 = (u16*)(ws + 0);        // 8MB  [A]
  u16*   normk16 = (u16*)(ws + 8  * MB);  // 8MB  [B]
  u16*   xq16    = (u16*)(ws + 16 * MB);  // 8MB  [C]
  u16*   pos16   = (u16*)(ws + 24 * MB);  // 1MB  [D]
  float* q_f32   = (float*)(ws + 25 * MB);// 16MB [E]
  u16*   k16     = (u16*)(ws + 41 * MB);  // 8MB  [F]
  u16*   v16     = (u16*)(ws + 49 * MB);  // 8MB  [G]
  u16*   r16     = (u16*)(ws + 57 * MB);  // 1MB  [H]
  float* tA      = (float*)(ws + 58 * MB);// 16MB
  float* tB      = (float*)(ws + 74 * MB);// 16MB
  float* tC      = (float*)(ws + 90 * MB);// 16MB  (total 106MB)
  // aliases over dead regions
  u16*   att16   = normq16;               // after q-GEMM consumed normq16
  u16*   Y16     = normk16;               // after k,v GEMMs
  u16*   rx16    = normq16;               // after Wo GEMM consumed att16
  float* out1    = (float*)(ws + 41 * MB);// over k16+v16 (dead after attn)
  u16*   out116  = (u16*)(ws + 25 * MB);  // over q_f32 lower half
  u16*   Ef16    = (u16*)(ws + 33 * MB);  // over q_f32 upper half
  u16*   ln2o16  = xq16;                  // after gate1 U-GEMMs

  auto gemm = [&](const u16* A, const float* W, const float* bias,
                  float* Cf, u16* Cb, int M, int beta, int relu) {
    dim3 grid(M / 128, 8);
    gemm_bt<<<grid, 256, 0, stream>>>(A, W, bias, Cf, Cb, M, 1024, 1024, beta, relu);
  };

  // --- stage 1: norms / conversions / pos encoding
  ln_kernel<<<4096, 256, 0, stream>>>(query, ln1_g, ln1_b, normq16);
  ln_kernel<<<4096, 256, 0, stream>>>(key,   ln1_g, ln1_b, normk16);
  cvt_kernel<<<4096, 256, 0, stream>>>(query, xq16);
  posenc_kernel<<<1024, 256, 0, stream>>>(pos16);

  // --- stage 2: projections
  gemm(normq16, Wq, bq, q_f32, nullptr, 4096, 0, 0);
  gemm(normk16, Wk, bk, nullptr, k16,   4096, 0, 0);
  gemm(normk16, Wv, bv, nullptr, v16,   4096, 0, 0);
  gemm(pos16,   Wp, nullptr, nullptr, r16, 512, 0, 0);

  // --- stage 3: attention + output projection
  attn_kernel<<<dim3(128, 16, 8), 256, 0, stream>>>(q_f32, k16, v16, r16,
                                                    u_bias, v_bias, att16);
  gemm(att16, Wo, bo, nullptr, Y16, 4096, 0, 0);

  // --- stage 4: GRU gate 1 (x=query, y=Y)
  gemm(Y16,  g1_Wr, nullptr, tA, nullptr, 4096, 0, 0);
  gemm(xq16, g1_Ur, nullptr, tA, nullptr, 4096, 1, 0);
  gemm(Y16,  g1_Wz, nullptr, tB, nullptr, 4096, 0, 0);
  gemm(xq16, g1_Uz, nullptr, tB, nullptr, 4096, 1, 0);
  gemm(Y16,  g1_Wg, nullptr, tC, nullptr, 4096, 0, 0);
  rx_kernel<<<4096, 256, 0, stream>>>(tA, query, rx16);
  gemm(rx16, g1_Ug, nullptr, tC, nullptr, 4096, 1, 0);
  combine_kernel<<<4096, 256, 0, stream>>>(tB, tC, query, out1, out116);

  // --- stage 5: FFN
  ln_kernel<<<4096, 256, 0, stream>>>(out1, ln2_g, ln2_b, ln2o16);
  gemm(ln2o16, fc_W, fc_b, nullptr, Ef16, 4096, 0, 1);

  // --- stage 6: GRU gate 2 (x=out1, y=Ef)
  gemm(Ef16,   g2_Wr, nullptr, tA, nullptr, 4096, 0, 0);
  gemm(out116, g2_Ur, nullptr, tA, nullptr, 4096, 1, 0);
  gemm(Ef16,   g2_Wz, nullptr, tB, nullptr, 4096, 0, 0);
  gemm(out116, g2_Uz, nullptr, tB, nullptr, 4096, 1, 0);
  gemm(Ef16,   g2_Wg, nullptr, tC, nullptr, 4096, 0, 0);
  rx_kernel<<<4096, 256, 0, stream>>>(tA, out1, rx16);
  gemm(rx16,   g2_Ug, nullptr, tC, nullptr, 4096, 1, 0);
  combine_kernel<<<4096, 256, 0, stream>>>(tB, tC, out1, (float*)d_out, nullptr);
}

// Round 2
// 1055.990 us; speedup vs baseline: 1.4543x; 1.4543x over previous
//
#include <hip/hip_runtime.h>

typedef unsigned short u16;
typedef __attribute__((ext_vector_type(8))) short short8;
typedef __attribute__((ext_vector_type(4))) float f32x4;

#define DEVFN __device__ __forceinline__

constexpr int Bc = 8, Sc = 512, Ec = 1024, Hc = 16, Dc = 64;

DEVFN u16 f2b(float f) {
  union { float f; unsigned u; } a; a.f = f;
  unsigned u = a.u;
  u += 0x7fffu + ((u >> 16) & 1u);   // RTNE to bf16
  return (u16)(u >> 16);
}
DEVFN float b2f(u16 h) {
  union { unsigned u; float f; } a; a.u = ((unsigned)h) << 16; return a.f;
}
DEVFN unsigned pack2(float a, float b) {
  return (unsigned)f2b(a) | ((unsigned)f2b(b) << 16);
}
DEVFN float wred_sum(float v) {
  #pragma unroll
  for (int o = 32; o; o >>= 1) v += __shfl_xor(v, o, 64);
  return v;
}

// ---------------------------------------------------------------------------
// GEMM: C[M,N] = A[M,K](bf16) @ W[N,K](f32, converted in-stage)^T  (+bias)(+C)
// 128x128 tile, BK=32, 4 waves (2x2), each wave 64x64 via 4x4 MFMA 16x16x32.
// ---------------------------------------------------------------------------
__global__ __launch_bounds__(256) void gemm_bt(
    const u16* __restrict__ Ap, const float* __restrict__ W,
    const float* __restrict__ bias, float* __restrict__ Cf,
    u16* __restrict__ Cb, int M, int N, int K, int beta, int relu,
    const float* __restrict__ b2a, const float* __restrict__ b2b,
    u16* __restrict__ Cb2)
{
  __shared__ u16 lA[128 * 40];
  __shared__ u16 lB[128 * 40];
  const int tid = threadIdx.x;
  const int m0 = blockIdx.x * 128, n0 = blockIdx.y * 128;
  const int wid = tid >> 6, lane = tid & 63;
  const int wm = (wid >> 1) * 64, wn = (wid & 1) * 64;
  const int r16i = lane & 15, kg = (lane >> 4) * 8;

  f32x4 zero = {0.f, 0.f, 0.f, 0.f};
  f32x4 acc[4][4];
  #pragma unroll
  for (int mi = 0; mi < 4; ++mi)
    #pragma unroll
    for (int ni = 0; ni < 4; ++ni) acc[mi][ni] = zero;

  for (int k0 = 0; k0 < K; k0 += 32) {
    #pragma unroll
    for (int rep = 0; rep < 2; ++rep) {
      int idx = tid + rep * 256;          // 0..511
      int row = idx >> 2, cb = (idx & 3) * 8;
      const u16* asrc = Ap + (size_t)(m0 + row) * K + k0 + cb;
      uint4 av = *(const uint4*)asrc;
      *(uint4*)&lA[row * 40 + cb] = av;
      const float* wsrc = W + (size_t)(n0 + row) * K + k0 + cb;
      float4 w0 = *(const float4*)wsrc;
      float4 w1 = *(const float4*)(wsrc + 4);
      uint4 wv;
      wv.x = pack2(w0.x, w0.y); wv.y = pack2(w0.z, w0.w);
      wv.z = pack2(w1.x, w1.y); wv.w = pack2(w1.z, w1.w);
      *(uint4*)&lB[row * 40 + cb] = wv;
    }
    __syncthreads();

    short8 afr[4], bfr[4];
    #pragma unroll
    for (int mi = 0; mi < 4; ++mi)
      afr[mi] = *(const short8*)&lA[(wm + mi * 16 + r16i) * 40 + kg];
    #pragma unroll
    for (int ni = 0; ni < 4; ++ni)
      bfr[ni] = *(const short8*)&lB[(wn + ni * 16 + r16i) * 40 + kg];
    #pragma unroll
    for (int mi = 0; mi < 4; ++mi)
      #pragma unroll
      for (int ni = 0; ni < 4; ++ni)
        acc[mi][ni] = __builtin_amdgcn_mfma_f32_16x16x32_bf16(
            afr[mi], bfr[ni], acc[mi][ni], 0, 0, 0);
    __syncthreads();
  }

  const int colb = n0 + wn + r16i;
  const int rowb = m0 + wm + (lane >> 4) * 4;
  #pragma unroll
  for (int mi = 0; mi < 4; ++mi) {
    #pragma unroll
    for (int ni = 0; ni < 4; ++ni) {
      int col = colb + ni * 16;
      float bv = bias ? bias[col] : 0.f;
      float ba = b2a ? b2a[col] : 0.f;
      float bb = b2b ? b2b[col] : 0.f;
      #pragma unroll
      for (int q = 0; q < 4; ++q) {
        int row = rowb + mi * 16 + q;
        size_t off = (size_t)row * N + col;
        float v = acc[mi][ni][q] + bv;
        if (Cb2) {
          Cb[off]  = f2b(v + ba);
          Cb2[off] = f2b(v + bb);
        } else {
          if (beta) v += Cf[off];
          if (relu) v = fmaxf(v, 0.f);
          if (Cf) Cf[off] = v;
          if (Cb) Cb[off] = f2b(v);
        }
      }
    }
  }
}

// ---------------------------------------------------------------------------
// LayerNorm over rows of 1024, fp32 in -> bf16 out
// ---------------------------------------------------------------------------
__global__ __launch_bounds__(256) void ln_kernel(
    const float* __restrict__ x, const float* __restrict__ g,
    const float* __restrict__ bb, u16* __restrict__ out)
{
  const int row = blockIdx.x, t = threadIdx.x;
  float4 xv = ((const float4*)x)[(size_t)row * 256 + t];
  float s  = xv.x + xv.y + xv.z + xv.w;
  float s2 = xv.x * xv.x + xv.y * xv.y + xv.z * xv.z + xv.w * xv.w;
  s = wred_sum(s); s2 = wred_sum(s2);
  __shared__ float sh[8];
  int wid = t >> 6, lane = t & 63;
  if (lane == 0) { sh[wid] = s; sh[4 + wid] = s2; }
  __syncthreads();
  s  = sh[0] + sh[1] + sh[2] + sh[3];
  s2 = sh[4] + sh[5] + sh[6] + sh[7];
  float mean = s * (1.f / 1024.f);
  float var  = s2 * (1.f / 1024.f) - mean * mean;
  float rstd = rsqrtf(var + 1e-5f);
  float4 gv = ((const float4*)g)[t];
  float4 bv = ((const float4*)bb)[t];
  uint2 o;
  o.x = pack2((xv.x - mean) * rstd * gv.x + bv.x,
              (xv.y - mean) * rstd * gv.y + bv.y);
  o.y = pack2((xv.z - mean) * rstd * gv.z + bv.z,
              (xv.w - mean) * rstd * gv.w + bv.w);
  *(uint2*)&out[(size_t)row * 1024 + t * 4] = o;
}

__global__ __launch_bounds__(256) void cvt_kernel(
    const float* __restrict__ x, u16* __restrict__ out)
{
  int i = blockIdx.x * 256 + threadIdx.x;
  float4 v = ((const float4*)x)[i];
  uint2 o; o.x = pack2(v.x, v.y); o.y = pack2(v.z, v.w);
  *(uint2*)&out[(size_t)i * 4] = o;
}

__global__ __launch_bounds__(256) void posenc_kernel(u16* __restrict__ out)
{
  int idx = blockIdx.x * 256 + threadIdx.x;   // 0..262143
  int i = idx >> 9, f = idx & 511;
  float pos = (float)(Sc - 1 - i);
  float invf = expf((float)f * -0.017988946039016f);
  float ang = pos * invf;
  out[(size_t)i * 1024 + f]       = f2b(sinf(ang));
  out[(size_t)i * 1024 + 512 + f] = f2b(cosf(ang));
}

// ---------------------------------------------------------------------------
// MFMA flash attention with fused Transformer-XL relative position term.
// Block: (qtile of 64 rows, h, b); 4 waves x 16 q-rows. Key tiles of 64.
// score(i,j) = ((q_i+u)�k_j + (q_i+vb)�r[511-i+j]) / 8,  j<=i.
// BD computed as a 16x80 band E then shift-read via LDS: BD[r,c]=EB[r][15-r+c].
// ---------------------------------------------------------------------------
__global__ __launch_bounds__(256) void attn_mfma(
    const u16* __restrict__ qu16, const u16* __restrict__ qv16,
    const u16* __restrict__ k16, const u16* __restrict__ v16,
    const u16* __restrict__ r16, u16* __restrict__ out)
{
  __shared__ u16   VT[64 * 88];        // V transposed [d][j], pad 88
  __shared__ float EB[4][16 * 85];     // per-wave E band, pad 85
  __shared__ u16   PW[4][16 * 72];     // per-wave P bf16, pad 72

  const int tid = threadIdx.x;
  const int wave = tid >> 6, lane = tid & 63;
  const int g = lane >> 4, c15 = lane & 15;
  const int qb = blockIdx.x;           // 0..7
  const int h = blockIdx.y, b = blockIdx.z;
  const int i0 = qb * 64;
  const int i0w = i0 + wave * 16;

  const size_t bh_off = ((size_t)b * Sc) * Ec + h * Dc;

  // A fragments for this wave's 16 q-rows (row = c15, k = kc*32 + g*8 + e)
  short8 qa[2], va[2];
  #pragma unroll
  for (int kc = 0; kc < 2; ++kc) {
    size_t o = bh_off + (size_t)(i0w + c15) * Ec + kc * 32 + g * 8;
    qa[kc] = *(const short8*)(qu16 + o);
    va[kc] = *(const short8*)(qv16 + o);
  }

  f32x4 oacc[4];
  #pragma unroll
  for (int t = 0; t < 4; ++t) oacc[t] = {0.f, 0.f, 0.f, 0.f};
  float m[4], l[4];
  #pragma unroll
  for (int q = 0; q < 4; ++q) { m[q] = -1e30f; l[q] = 0.f; }

  float* eb = EB[wave];
  u16*   pw = PW[wave];

  const int NT = qb + 1;
  for (int jt = 0; jt < NT; ++jt) {
    const int j0 = jt * 64;
    __syncthreads();   // protect VT from previous iteration's readers
    {
      int j = tid >> 2, d0 = (tid & 3) * 16;
      const u16* src = v16 + bh_off + (size_t)(j0 + j) * Ec + d0;
      uint4 a0 = *(const uint4*)src;
      uint4 a1 = *(const uint4*)(src + 8);
      u16 vals[16];
      *(uint4*)&vals[0] = a0; *(uint4*)&vals[8] = a1;
      #pragma unroll
      for (int e = 0; e < 16; ++e)
        VT[(d0 + e) * 88 + j] = vals[e];
    }
    __syncthreads();

    // ---- AC = (q+u) K^T  [16 x 64] ----
    f32x4 ac[4];
    #pragma unroll
    for (int t = 0; t < 4; ++t) ac[t] = {0.f, 0.f, 0.f, 0.f};
    #pragma unroll
    for (int kc = 0; kc < 2; ++kc)
      #pragma unroll
      for (int nt = 0; nt < 4; ++nt) {
        size_t o = bh_off + (size_t)(j0 + nt * 16 + c15) * Ec + kc * 32 + g * 8;
        short8 kb = *(const short8*)(k16 + o);
        ac[nt] = __builtin_amdgcn_mfma_f32_16x16x32_bf16(qa[kc], kb, ac[nt], 0, 0, 0);
      }

    // ---- E band = (q+vb) R^T  [16 x 80] ----
    const int t0 = 496 - i0w + j0;
    f32x4 e5[5];
    #pragma unroll
    for (int t = 0; t < 5; ++t) e5[t] = {0.f, 0.f, 0.f, 0.f};
    #pragma unroll
    for (int kc = 0; kc < 2; ++kc)
      #pragma unroll
      for (int nt = 0; nt < 5; ++nt) {
        int t = t0 + nt * 16 + c15; t = t > 511 ? 511 : t;
        size_t o = (size_t)t * Ec + h * Dc + kc * 32 + g * 8;
        short8 rb = *(const short8*)(r16 + o);
        e5[nt] = __builtin_amdgcn_mfma_f32_16x16x32_bf16(va[kc], rb, e5[nt], 0, 0, 0);
      }
    #pragma unroll
    for (int nt = 0; nt < 5; ++nt)
      #pragma unroll
      for (int q = 0; q < 4; ++q)
        eb[(g * 4 + q) * 85 + nt * 16 + c15] = e5[nt][q];

    // ---- combine + mask ----
    float s[4][4];
    #pragma unroll
    for (int ct = 0; ct < 4; ++ct) {
      int jcol = j0 + ct * 16 + c15;
      #pragma unroll
      for (int q = 0; q < 4; ++q) {
        int r = g * 4 + q;
        float bd = eb[84 * r + 15 + ct * 16 + c15];   // = EB[r][(15-r)+c]
        float sv = (ac[ct][q] + bd) * 0.125f;
        s[ct][q] = (jcol <= i0w + r) ? sv : -1e30f;
      }
    }

    // ---- online softmax (rows live across lane&15) ----
    float mnew[4], csc[4];
    #pragma unroll
    for (int q = 0; q < 4; ++q) {
      float mx = fmaxf(fmaxf(s[0][q], s[1][q]), fmaxf(s[2][q], s[3][q]));
      #pragma unroll
      for (int o = 8; o; o >>= 1) mx = fmaxf(mx, __shfl_xor(mx, o, 64));
      mnew[q] = fmaxf(m[q], mx);
      csc[q] = expf(m[q] - mnew[q]);
      m[q] = mnew[q];
    }
    float rs[4] = {0.f, 0.f, 0.f, 0.f};
    float p[4][4];
    #pragma unroll
    for (int ct = 0; ct < 4; ++ct)
      #pragma unroll
      for (int q = 0; q < 4; ++q) {
        p[ct][q] = expf(s[ct][q] - mnew[q]);
        rs[q] += p[ct][q];
      }
    #pragma unroll
    for (int q = 0; q < 4; ++q) {
      float t = rs[q];
      #pragma unroll
      for (int o = 8; o; o >>= 1) t += __shfl_xor(t, o, 64);
      l[q] = l[q] * csc[q] + t;
      #pragma unroll
      for (int ct = 0; ct < 4; ++ct) oacc[ct][q] *= csc[q];
    }

    // ---- P -> bf16 via LDS transpose, then PV MFMA ----
    #pragma unroll
    for (int ct = 0; ct < 4; ++ct)
      #pragma unroll
      for (int q = 0; q < 4; ++q)
        pw[(g * 4 + q) * 72 + ct * 16 + c15] = f2b(p[ct][q]);

    #pragma unroll
    for (int kc = 0; kc < 2; ++kc) {
      short8 pa = *(const short8*)&pw[c15 * 72 + kc * 32 + g * 8];
      #pragma unroll
      for (int nt = 0; nt < 4; ++nt) {
        short8 vb8 = *(const short8*)&VT[(nt * 16 + c15) * 88 + kc * 32 + g * 8];
        oacc[nt] = __builtin_amdgcn_mfma_f32_16x16x32_bf16(pa, vb8, oacc[nt], 0, 0, 0);
      }
    }
  }

  #pragma unroll
  for (int q = 0; q < 4; ++q) {
    float rl = 1.f / l[q];
    size_t ro = bh_off + (size_t)(i0w + g * 4 + q) * Ec;
    #pragma unroll
    for (int ct = 0; ct < 4; ++ct)
      out[ro + ct * 16 + c15] = f2b(oacc[ct][q] * rl);
  }
}

// rx = bf16( sigmoid(tA) * x )
__global__ __launch_bounds__(256) void rx_kernel(
    const float* __restrict__ tA, const float* __restrict__ x,
    u16* __restrict__ out)
{
  int i = blockIdx.x * 256 + threadIdx.x;
  float4 a  = ((const float4*)tA)[i];
  float4 xv = ((const float4*)x)[i];
  float r0 = 1.f / (1.f + expf(-a.x));
  float r1 = 1.f / (1.f + expf(-a.y));
  float r2 = 1.f / (1.f + expf(-a.z));
  float r3 = 1.f / (1.f + expf(-a.w));
  uint2 o;
  o.x = pack2(r0 * xv.x, r1 * xv.y);
  o.y = pack2(r2 * xv.z, r3 * xv.w);
  *(uint2*)&out[(size_t)i * 4] = o;
}

// out = (1-z)*x + z*tanh(tC),  z = sigmoid(tB - 2)
__global__ __launch_bounds__(256) void combine_kernel(
    const float* __restrict__ tB, const float* __restrict__ tC,
    const float* __restrict__ x, float* __restrict__ outf,
    u16* __restrict__ outb)
{
  int i = blockIdx.x * 256 + threadIdx.x;
  float4 zb = ((const float4*)tB)[i];
  float4 hc = ((const float4*)tC)[i];
  float4 xv = ((const float4*)x)[i];
  float z0 = 1.f / (1.f + expf(-(zb.x - 2.f)));
  float z1 = 1.f / (1.f + expf(-(zb.y - 2.f)));
  float z2 = 1.f / (1.f + expf(-(zb.z - 2.f)));
  float z3 = 1.f / (1.f + expf(-(zb.w - 2.f)));
  float4 r;
  r.x = (1.f - z0) * xv.x + z0 * tanhf(hc.x);
  r.y = (1.f - z1) * xv.y + z1 * tanhf(hc.y);
  r.z = (1.f - z2) * xv.z + z2 * tanhf(hc.z);
  r.w = (1.f - z3) * xv.w + z3 * tanhf(hc.w);
  ((float4*)outf)[i] = r;
  if (outb) {
    uint2 o; o.x = pack2(r.x, r.y); o.y = pack2(r.z, r.w);
    *(uint2*)&outb[(size_t)i * 4] = o;
  }
}

// ---------------------------------------------------------------------------
extern "C" void kernel_launch(void* const* d_in, const int* in_sizes, int n_in,
                              void* d_out, int out_size, void* d_ws, size_t ws_size,
                              hipStream_t stream) {
  (void)in_sizes; (void)n_in; (void)out_size; (void)ws_size;

  const float* query = (const float*)d_in[0];
  const float* key   = (const float*)d_in[1];
  const float* ln1_g = (const float*)d_in[4];
  const float* ln1_b = (const float*)d_in[5];
  const float* ln2_g = (const float*)d_in[6];
  const float* ln2_b = (const float*)d_in[7];
  const float* Wq = (const float*)d_in[8];   const float* bq = (const float*)d_in[9];
  const float* Wk = (const float*)d_in[10];  const float* bk = (const float*)d_in[11];
  const float* Wv = (const float*)d_in[12];  const float* bv = (const float*)d_in[13];
  const float* Wp = (const float*)d_in[14];
  const float* Wo = (const float*)d_in[15];  const float* bo = (const float*)d_in[16];
  const float* u_bias = (const float*)d_in[17];
  const float* v_bias = (const float*)d_in[18];
  const float* g1_Wr = (const float*)d_in[19]; const float* g1_Ur = (const float*)d_in[20];
  const float* g1_Wz = (const float*)d_in[21]; const float* g1_Uz = (const float*)d_in[22];
  const float* g1_Wg = (const float*)d_in[23]; const float* g1_Ug = (const float*)d_in[24];
  const float* g2_Wr = (const float*)d_in[25]; const float* g2_Ur = (const float*)d_in[26];
  const float* g2_Wz = (const float*)d_in[27]; const float* g2_Uz = (const float*)d_in[28];
  const float* g2_Wg = (const float*)d_in[29]; const float* g2_Ug = (const float*)d_in[30];
  const float* fc_W = (const float*)d_in[31]; const float* fc_b = (const float*)d_in[32];

  const size_t MB = 1ull << 20;
  char* ws = (char*)d_ws;
  u16*   normq16 = (u16*)(ws + 0);        // 8MB
  u16*   normk16 = (u16*)(ws + 8  * MB);  // 8MB
  u16*   xq16    = (u16*)(ws + 16 * MB);  // 8MB
  u16*   pos16   = (u16*)(ws + 24 * MB);  // 1MB
  u16*   qu16    = (u16*)(ws + 25 * MB);  // 8MB
  u16*   qv16    = (u16*)(ws + 33 * MB);  // 8MB
  u16*   k16     = (u16*)(ws + 41 * MB);  // 8MB
  u16*   v16     = (u16*)(ws + 49 * MB);  // 8MB
  u16*   r16     = (u16*)(ws + 57 * MB);  // 1MB
  float* tA      = (float*)(ws + 58 * MB);// 16MB
  float* tB      = (float*)(ws + 74 * MB);// 16MB
  float* tC      = (float*)(ws + 90 * MB);// 16MB
  // aliases over dead regions
  u16*   att16   = normq16;               // after q GEMM consumed normq16
  u16*   Y16     = normk16;               // after k,v GEMMs
  u16*   rx16    = normq16;               // after Wo GEMM consumed att16
  float* out1    = (float*)(ws + 41 * MB);// over k16+v16 (dead after attn)
  u16*   out116  = (u16*)(ws + 25 * MB);  // over qu16 (dead after attn)
  u16*   Ef16    = (u16*)(ws + 33 * MB);  // over qv16 (dead after attn)
  u16*   ln2o16  = xq16;                  // after gate1 U-GEMMs

  auto gemm = [&](const u16* A, const float* W, const float* bias,
                  float* Cf, u16* Cb, int M, int beta, int relu) {
    dim3 grid(M / 128, 8);
    gemm_bt<<<grid, 256, 0, stream>>>(A, W, bias, Cf, Cb, M, 1024, 1024,
                                      beta, relu, nullptr, nullptr, nullptr);
  };

  // --- stage 1: norms / conversions / pos encoding
  ln_kernel<<<4096, 256, 0, stream>>>(query, ln1_g, ln1_b, normq16);
  ln_kernel<<<4096, 256, 0, stream>>>(key,   ln1_g, ln1_b, normk16);
  cvt_kernel<<<4096, 256, 0, stream>>>(query, xq16);
  posenc_kernel<<<1024, 256, 0, stream>>>(pos16);

  // --- stage 2: projections (q writes qu=q+u, qv=q+vb directly)
  gemm_bt<<<dim3(32, 8), 256, 0, stream>>>(normq16, Wq, bq, nullptr, qu16,
                                           4096, 1024, 1024, 0, 0,
                                           u_bias, v_bias, qv16);
  gemm(normk16, Wk, bk, nullptr, k16, 4096, 0, 0);
  gemm(normk16, Wv, bv, nullptr, v16, 4096, 0, 0);
  gemm(pos16,   Wp, nullptr, nullptr, r16, 512, 0, 0);

  // --- stage 3: attention + output projection
  attn_mfma<<<dim3(8, 16, 8), 256, 0, stream>>>(qu16, qv16, k16, v16, r16, att16);
  gemm(att16, Wo, bo, nullptr, Y16, 4096, 0, 0);

  // --- stage 4: GRU gate 1 (x=query, y=Y)
  gemm(Y16,  g1_Wr, nullptr, tA, nullptr, 4096, 0, 0);
  gemm(xq16, g1_Ur, nullptr, tA, nullptr, 4096, 1, 0);
  gemm(Y16,  g1_Wz, nullptr, tB, nullptr, 4096, 0, 0);
  gemm(xq16, g1_Uz, nullptr, tB, nullptr, 4096, 1, 0);
  gemm(Y16,  g1_Wg, nullptr, tC, nullptr, 4096, 0, 0);
  rx_kernel<<<4096, 256, 0, stream>>>(tA, query, rx16);
  gemm(rx16, g1_Ug, nullptr, tC, nullptr, 4096, 1, 0);
  combine_kernel<<<4096, 256, 0, stream>>>(tB, tC, query, out1, out116);

  // --- stage 5: FFN
  ln_kernel<<<4096, 256, 0, stream>>>(out1, ln2_g, ln2_b, ln2o16);
  gemm(ln2o16, fc_W, fc_b, nullptr, Ef16, 4096, 0, 1);

  // --- stage 6: GRU gate 2 (x=out1, y=Ef)
  gemm(Ef16,   g2_Wr, nullptr, tA, nullptr, 4096, 0, 0);
  gemm(out116, g2_Ur, nullptr, tA, nullptr, 4096, 1, 0);
  gemm(Ef16,   g2_Wz, nullptr, tB, nullptr, 4096, 0, 0);
  gemm(out116, g2_Uz, nullptr, tB, nullptr, 4096, 1, 0);
  gemm(Ef16,   g2_Wg, nullptr, tC, nullptr, 4096, 0, 0);
  rx_kernel<<<4096, 256, 0, stream>>>(tA, out1, rx16);
  gemm(rx16,   g2_Ug, nullptr, tC, nullptr, 4096, 1, 0);
  combine_kernel<<<4096, 256, 0, stream>>>(tB, tC, out1, (float*)d_out, nullptr);
}

// Round 3
// 628.005 us; speedup vs baseline: 2.4454x; 1.6815x over previous
//
#include <hip/hip_runtime.h>

typedef unsigned short u16;
typedef __attribute__((ext_vector_type(8))) short short8;
typedef __attribute__((ext_vector_type(4))) float f32x4;

#define DEVFN __device__ __forceinline__

constexpr int Bc = 8, Sc = 512, Ec = 1024, Hc = 16, Dc = 64;

DEVFN u16 f2b(float f) {
  union { float f; unsigned u; } a; a.f = f;
  unsigned u = a.u;
  u += 0x7fffu + ((u >> 16) & 1u);   // RTNE to bf16
  return (u16)(u >> 16);
}
DEVFN float b2f(u16 h) {
  union { unsigned u; float f; } a; a.u = ((unsigned)h) << 16; return a.f;
}
DEVFN unsigned pack2(float a, float b) {
  return (unsigned)f2b(a) | ((unsigned)f2b(b) << 16);
}
DEVFN float wred_sum(float v) {
  #pragma unroll
  for (int o = 32; o; o >>= 1) v += __shfl_xor(v, o, 64);
  return v;
}
DEVFN void gload16(const void* g, void* l) {
  __builtin_amdgcn_global_load_lds(
      (const __attribute__((address_space(1))) void*)g,
      (__attribute__((address_space(3))) void*)l, 16, 0, 0);
}

// ---------------------------------------------------------------------------
// Weight pre-conversion: 18 matrices of 1024x1024 f32 -> bf16
// ---------------------------------------------------------------------------
struct PtrBundle { const float* src[18]; u16* dst[18]; };

__global__ __launch_bounds__(256) void cvtw_kernel(PtrBundle pb)
{
  int w = blockIdx.y;
  int i = blockIdx.x * 256 + threadIdx.x;          // 1M elems / 4 per thread
  float4 v = ((const float4*)pb.src[w])[i];
  uint2 o; o.x = pack2(v.x, v.y); o.y = pack2(v.z, v.w);
  ((uint2*)pb.dst[w])[i] = o;
}

// ---------------------------------------------------------------------------
// Fused GEMM: C[M,N] = A@W1^T (+ A2@W2^T), A bf16 [M,1024], W bf16 [1024,1024].
// 128xTN tile, BK=32, global_load_lds staging, 4 waves (2x2),
// per-wave 64x(TN/2) via 4xNI MFMA 16x16x32. Epilogue variants fused.
// blockIdx.y selects segment (weight set + epilogue) and N-tile.
// ---------------------------------------------------------------------------
struct GemmSeg {
  const u16* A1; const u16* A2;      // A2 != null -> dual-K (K=2048)
  const u16* W1; const u16* W2;
  const float* bias;                 // added to acc (may be null)
  const float* bu; const float* bv;  // epi 1: second/third bias
  const float* xF;                   // epi 3/4: f32 x input
  const float* zF;                   // epi 4: f32 z-preact
  u16* o16a; u16* o16b;              // bf16 outputs
  float* oF;                         // f32 output
  int epi;                           // 0 b16 | 1 qkv-q | 2 f32 | 3 rx | 4 combine | 5 relu
};
struct GemmDesc { GemmSeg seg[3]; };

template<int TN>
__global__ __launch_bounds__(256) void gemm_f(GemmDesc dd)
{
  constexpr int NI = TN / 32;
  constexpr int BPS = 1024 / TN;
  __shared__ u16 lA[128 * 32];
  __shared__ u16 lB[TN * 32];
  const int tid = threadIdx.x;
  const GemmSeg s = dd.seg[blockIdx.y / BPS];
  const int n0 = (blockIdx.y % BPS) * TN;
  const int m0 = blockIdx.x * 128;
  const int wid = tid >> 6, lane = tid & 63;
  const int wm = (wid >> 1) * 64, wn = (wid & 1) * (TN / 2);
  const int c15 = lane & 15, g8 = (lane >> 4) * 8;
  const int arow = tid >> 2, ac8 = (tid & 3) * 8;   // staging chunk -> row/col

  f32x4 acc[4][NI];
  #pragma unroll
  for (int mi = 0; mi < 4; ++mi)
    #pragma unroll
    for (int ni = 0; ni < NI; ++ni) acc[mi][ni] = {0.f, 0.f, 0.f, 0.f};

  const int nseg = s.A2 ? 2 : 1;
  for (int sg = 0; sg < nseg; ++sg) {
    const u16* Abase = (sg ? s.A2 : s.A1) + (size_t)m0 * 1024;
    const u16* Wbase = (sg ? s.W2 : s.W1) + (size_t)n0 * 1024;
    for (int k0 = 0; k0 < 1024; k0 += 32) {
      gload16(Abase + (size_t)arow * 1024 + k0 + ac8,        &lA[tid * 8]);
      gload16(Abase + (size_t)(arow + 64) * 1024 + k0 + ac8, &lA[2048 + tid * 8]);
      gload16(Wbase + (size_t)arow * 1024 + k0 + ac8,        &lB[tid * 8]);
      if constexpr (TN == 128)
        gload16(Wbase + (size_t)(arow + 64) * 1024 + k0 + ac8, &lB[2048 + tid * 8]);
      __syncthreads();

      short8 afr[4], bfr[NI];
      #pragma unroll
      for (int mi = 0; mi < 4; ++mi)
        afr[mi] = *(const short8*)&lA[(wm + mi * 16 + c15) * 32 + g8];
      #pragma unroll
      for (int ni = 0; ni < NI; ++ni)
        bfr[ni] = *(const short8*)&lB[(wn + ni * 16 + c15) * 32 + g8];
      #pragma unroll
      for (int mi = 0; mi < 4; ++mi)
        #pragma unroll
        for (int ni = 0; ni < NI; ++ni)
          acc[mi][ni] = __builtin_amdgcn_mfma_f32_16x16x32_bf16(
              afr[mi], bfr[ni], acc[mi][ni], 0, 0, 0);
      __syncthreads();
    }
  }

  const int colb = n0 + wn + c15;
  const int rowb = m0 + wm + (lane >> 4) * 4;
  #pragma unroll
  for (int ni = 0; ni < NI; ++ni) {
    int col = colb + ni * 16;
    float bb = s.bias ? s.bias[col] : 0.f;
    float bu = 0.f, bvv = 0.f;
    if (s.epi == 1) { bu = s.bu[col]; bvv = s.bv[col]; }
    #pragma unroll
    for (int mi = 0; mi < 4; ++mi) {
      #pragma unroll
      for (int q = 0; q < 4; ++q) {
        int row = rowb + mi * 16 + q;
        size_t off = (size_t)row * 1024 + col;
        float v = acc[mi][ni][q] + bb;
        switch (s.epi) {
          case 0: s.o16a[off] = f2b(v); break;
          case 1: s.o16a[off] = f2b(v + bu); s.o16b[off] = f2b(v + bvv); break;
          case 2: s.oF[off] = v; break;
          case 3: { float sg1 = 1.f / (1.f + expf(-v));
                    s.o16a[off] = f2b(sg1 * s.xF[off]); } break;
          case 4: { float z = 1.f / (1.f + expf(-(s.zF[off] - 2.f)));
                    float r = (1.f - z) * s.xF[off] + z * tanhf(v);
                    s.oF[off] = r;
                    if (s.o16a) s.o16a[off] = f2b(r); } break;
          case 5: s.o16a[off] = f2b(fmaxf(v, 0.f)); break;
        }
      }
    }
  }
}

// ---------------------------------------------------------------------------
// LayerNorm over rows of 1024, fp32 in -> bf16 out
// ---------------------------------------------------------------------------
__global__ __launch_bounds__(256) void ln_kernel(
    const float* __restrict__ x, const float* __restrict__ g,
    const float* __restrict__ bb, u16* __restrict__ out)
{
  const int row = blockIdx.x, t = threadIdx.x;
  float4 xv = ((const float4*)x)[(size_t)row * 256 + t];
  float s  = xv.x + xv.y + xv.z + xv.w;
  float s2 = xv.x * xv.x + xv.y * xv.y + xv.z * xv.z + xv.w * xv.w;
  s = wred_sum(s); s2 = wred_sum(s2);
  __shared__ float sh[8];
  int wid = t >> 6, lane = t & 63;
  if (lane == 0) { sh[wid] = s; sh[4 + wid] = s2; }
  __syncthreads();
  s  = sh[0] + sh[1] + sh[2] + sh[3];
  s2 = sh[4] + sh[5] + sh[6] + sh[7];
  float mean = s * (1.f / 1024.f);
  float var  = s2 * (1.f / 1024.f) - mean * mean;
  float rstd = rsqrtf(var + 1e-5f);
  float4 gv = ((const float4*)g)[t];
  float4 bv = ((const float4*)bb)[t];
  uint2 o;
  o.x = pack2((xv.x - mean) * rstd * gv.x + bv.x,
              (xv.y - mean) * rstd * gv.y + bv.y);
  o.y = pack2((xv.z - mean) * rstd * gv.z + bv.z,
              (xv.w - mean) * rstd * gv.w + bv.w);
  *(uint2*)&out[(size_t)row * 1024 + t * 4] = o;
}

__global__ __launch_bounds__(256) void cvt_kernel(
    const float* __restrict__ x, u16* __restrict__ out)
{
  int i = blockIdx.x * 256 + threadIdx.x;
  float4 v = ((const float4*)x)[i];
  uint2 o; o.x = pack2(v.x, v.y); o.y = pack2(v.z, v.w);
  *(uint2*)&out[(size_t)i * 4] = o;
}

__global__ __launch_bounds__(256) void posenc_kernel(u16* __restrict__ out)
{
  int idx = blockIdx.x * 256 + threadIdx.x;   // 0..262143
  int i = idx >> 9, f = idx & 511;
  float pos = (float)(Sc - 1 - i);
  float invf = expf((float)f * -0.017988946039016f);
  float ang = pos * invf;
  out[(size_t)i * 1024 + f]       = f2b(sinf(ang));
  out[(size_t)i * 1024 + 512 + f] = f2b(cosf(ang));
}

// ---------------------------------------------------------------------------
// MFMA flash attention with fused Transformer-XL relative position term.
// ---------------------------------------------------------------------------
__global__ __launch_bounds__(256) void attn_mfma(
    const u16* __restrict__ qu16, const u16* __restrict__ qv16,
    const u16* __restrict__ k16, const u16* __restrict__ v16,
    const u16* __restrict__ r16, u16* __restrict__ out)
{
  __shared__ u16   VT[64 * 88];        // V transposed [d][j], pad 88
  __shared__ float EB[4][16 * 85];     // per-wave E band, pad 85
  __shared__ u16   PW[4][16 * 72];     // per-wave P bf16, pad 72

  const int tid = threadIdx.x;
  const int wave = tid >> 6, lane = tid & 63;
  const int g = lane >> 4, c15 = lane & 15;
  const int qb = blockIdx.x;           // 0..7
  const int h = blockIdx.y, b = blockIdx.z;
  const int i0 = qb * 64;
  const int i0w = i0 + wave * 16;

  const size_t bh_off = ((size_t)b * Sc) * Ec + h * Dc;

  short8 qa[2], va[2];
  #pragma unroll
  for (int kc = 0; kc < 2; ++kc) {
    size_t o = bh_off + (size_t)(i0w + c15) * Ec + kc * 32 + g * 8;
    qa[kc] = *(const short8*)(qu16 + o);
    va[kc] = *(const short8*)(qv16 + o);
  }

  f32x4 oacc[4];
  #pragma unroll
  for (int t = 0; t < 4; ++t) oacc[t] = {0.f, 0.f, 0.f, 0.f};
  float m[4], l[4];
  #pragma unroll
  for (int q = 0; q < 4; ++q) { m[q] = -1e30f; l[q] = 0.f; }

  float* eb = EB[wave];
  u16*   pw = PW[wave];

  const int NT = qb + 1;
  for (int jt = 0; jt < NT; ++jt) {
    const int j0 = jt * 64;
    __syncthreads();
    {
      int j = tid >> 2, d0 = (tid & 3) * 16;
      const u16* src = v16 + bh_off + (size_t)(j0 + j) * Ec + d0;
      uint4 a0 = *(const uint4*)src;
      uint4 a1 = *(const uint4*)(src + 8);
      u16 vals[16];
      *(uint4*)&vals[0] = a0; *(uint4*)&vals[8] = a1;
      #pragma unroll
      for (int e = 0; e < 16; ++e)
        VT[(d0 + e) * 88 + j] = vals[e];
    }
    __syncthreads();

    f32x4 ac[4];
    #pragma unroll
    for (int t = 0; t < 4; ++t) ac[t] = {0.f, 0.f, 0.f, 0.f};
    #pragma unroll
    for (int kc = 0; kc < 2; ++kc)
      #pragma unroll
      for (int nt = 0; nt < 4; ++nt) {
        size_t o = bh_off + (size_t)(j0 + nt * 16 + c15) * Ec + kc * 32 + g * 8;
        short8 kb = *(const short8*)(k16 + o);
        ac[nt] = __builtin_amdgcn_mfma_f32_16x16x32_bf16(qa[kc], kb, ac[nt], 0, 0, 0);
      }

    const int t0 = 496 - i0w + j0;
    f32x4 e5[5];
    #pragma unroll
    for (int t = 0; t < 5; ++t) e5[t] = {0.f, 0.f, 0.f, 0.f};
    #pragma unroll
    for (int kc = 0; kc < 2; ++kc)
      #pragma unroll
      for (int nt = 0; nt < 5; ++nt) {
        int t = t0 + nt * 16 + c15; t = t > 511 ? 511 : t;
        size_t o = (size_t)t * Ec + h * Dc + kc * 32 + g * 8;
        short8 rb = *(const short8*)(r16 + o);
        e5[nt] = __builtin_amdgcn_mfma_f32_16x16x32_bf16(va[kc], rb, e5[nt], 0, 0, 0);
      }
    #pragma unroll
    for (int nt = 0; nt < 5; ++nt)
      #pragma unroll
      for (int q = 0; q < 4; ++q)
        eb[(g * 4 + q) * 85 + nt * 16 + c15] = e5[nt][q];

    float s[4][4];
    #pragma unroll
    for (int ct = 0; ct < 4; ++ct) {
      int jcol = j0 + ct * 16 + c15;
      #pragma unroll
      for (int q = 0; q < 4; ++q) {
        int r = g * 4 + q;
        float bd = eb[84 * r + 15 + ct * 16 + c15];
        float sv = (ac[ct][q] + bd) * 0.125f;
        s[ct][q] = (jcol <= i0w + r) ? sv : -1e30f;
      }
    }

    float mnew[4], csc[4];
    #pragma unroll
    for (int q = 0; q < 4; ++q) {
      float mx = fmaxf(fmaxf(s[0][q], s[1][q]), fmaxf(s[2][q], s[3][q]));
      #pragma unroll
      for (int o = 8; o; o >>= 1) mx = fmaxf(mx, __shfl_xor(mx, o, 64));
      mnew[q] = fmaxf(m[q], mx);
      csc[q] = expf(m[q] - mnew[q]);
      m[q] = mnew[q];
    }
    float rs[4] = {0.f, 0.f, 0.f, 0.f};
    float p[4][4];
    #pragma unroll
    for (int ct = 0; ct < 4; ++ct)
      #pragma unroll
      for (int q = 0; q < 4; ++q) {
        p[ct][q] = expf(s[ct][q] - mnew[q]);
        rs[q] += p[ct][q];
      }
    #pragma unroll
    for (int q = 0; q < 4; ++q) {
      float t = rs[q];
      #pragma unroll
      for (int o = 8; o; o >>= 1) t += __shfl_xor(t, o, 64);
      l[q] = l[q] * csc[q] + t;
      #pragma unroll
      for (int ct = 0; ct < 4; ++ct) oacc[ct][q] *= csc[q];
    }

    #pragma unroll
    for (int ct = 0; ct < 4; ++ct)
      #pragma unroll
      for (int q = 0; q < 4; ++q)
        pw[(g * 4 + q) * 72 + ct * 16 + c15] = f2b(p[ct][q]);

    #pragma unroll
    for (int kc = 0; kc < 2; ++kc) {
      short8 pa = *(const short8*)&pw[c15 * 72 + kc * 32 + g * 8];
      #pragma unroll
      for (int nt = 0; nt < 4; ++nt) {
        short8 vb8 = *(const short8*)&VT[(nt * 16 + c15) * 88 + kc * 32 + g * 8];
        oacc[nt] = __builtin_amdgcn_mfma_f32_16x16x32_bf16(pa, vb8, oacc[nt], 0, 0, 0);
      }
    }
  }

  #pragma unroll
  for (int q = 0; q < 4; ++q) {
    float rl = 1.f / l[q];
    size_t ro = bh_off + (size_t)(i0w + g * 4 + q) * Ec;
    #pragma unroll
    for (int ct = 0; ct < 4; ++ct)
      out[ro + ct * 16 + c15] = f2b(oacc[ct][q] * rl);
  }
}

// ---------------------------------------------------------------------------
extern "C" void kernel_launch(void* const* d_in, const int* in_sizes, int n_in,
                              void* d_out, int out_size, void* d_ws, size_t ws_size,
                              hipStream_t stream) {
  (void)in_sizes; (void)n_in; (void)out_size; (void)ws_size;

  const float* query = (const float*)d_in[0];
  const float* key   = (const float*)d_in[1];
  const float* ln1_g = (const float*)d_in[4];
  const float* ln1_b = (const float*)d_in[5];
  const float* ln2_g = (const float*)d_in[6];
  const float* ln2_b = (const float*)d_in[7];
  const float* Wq = (const float*)d_in[8];   const float* bq = (const float*)d_in[9];
  const float* Wk = (const float*)d_in[10];  const float* bk = (const float*)d_in[11];
  const float* Wv = (const float*)d_in[12];  const float* bv_in = (const float*)d_in[13];
  const float* Wp = (const float*)d_in[14];
  const float* Wo = (const float*)d_in[15];  const float* bo = (const float*)d_in[16];
  const float* u_bias = (const float*)d_in[17];
  const float* v_bias = (const float*)d_in[18];
  const float* fc_W = (const float*)d_in[31]; const float* fc_b = (const float*)d_in[32];

  const size_t MB = 1ull << 20;
  char* ws = (char*)d_ws;
  // 18 bf16 weights, 2MB each: [Wq Wk Wv Wp Wo fc | g1 Wr Ur Wz Uz Wg Ug | g2 ...]
  u16* wb[18];
  for (int i = 0; i < 18; ++i) wb[i] = (u16*)(ws + (size_t)i * 2 * MB);
  u16*   normq16 = (u16*)(ws + 36 * MB);  // -> att16 -> rx16
  u16*   normk16 = (u16*)(ws + 44 * MB);  // -> Y16
  u16*   xq16    = (u16*)(ws + 52 * MB);  // -> ln2o16
  u16*   pos16   = (u16*)(ws + 60 * MB);
  u16*   r16     = (u16*)(ws + 61 * MB);
  u16*   qu16    = (u16*)(ws + 62 * MB);  // -> out116
  u16*   qv16    = (u16*)(ws + 70 * MB);  // -> Ef16
  u16*   k16     = (u16*)(ws + 78 * MB);  // \ -> tB f32 (16MB)
  u16*   v16     = (u16*)(ws + 86 * MB);  // /
  float* out1    = (float*)(ws + 94 * MB);// 16MB
  u16*   att16   = normq16;
  u16*   Y16     = normk16;
  u16*   rx16    = normq16;
  u16*   out116  = qu16;
  u16*   Ef16    = qv16;
  u16*   ln2o16  = xq16;
  float* tB      = (float*)k16;

  // --- weight conversion ---
  PtrBundle pb;
  const float* wsrc[18] = {Wq, Wk, Wv, Wp, Wo, fc_W,
                           (const float*)d_in[19], (const float*)d_in[20],
                           (const float*)d_in[21], (const float*)d_in[22],
                           (const float*)d_in[23], (const float*)d_in[24],
                           (const float*)d_in[25], (const float*)d_in[26],
                           (const float*)d_in[27], (const float*)d_in[28],
                           (const float*)d_in[29], (const float*)d_in[30]};
  for (int i = 0; i < 18; ++i) { pb.src[i] = wsrc[i]; pb.dst[i] = wb[i]; }
  cvtw_kernel<<<dim3(1024, 18), 256, 0, stream>>>(pb);

  // --- stage 1 ---
  ln_kernel<<<4096, 256, 0, stream>>>(query, ln1_g, ln1_b, normq16);
  ln_kernel<<<4096, 256, 0, stream>>>(key,   ln1_g, ln1_b, normk16);
  cvt_kernel<<<4096, 256, 0, stream>>>(query, xq16);
  posenc_kernel<<<1024, 256, 0, stream>>>(pos16);

  GemmSeg z{}; GemmDesc d;

  // --- QKV fused (grid 32x24, TN=128) ---
  d.seg[0] = z; d.seg[0].A1 = normq16; d.seg[0].W1 = wb[0]; d.seg[0].bias = bq;
  d.seg[0].bu = u_bias; d.seg[0].bv = v_bias;
  d.seg[0].o16a = qu16; d.seg[0].o16b = qv16; d.seg[0].epi = 1;
  d.seg[1] = z; d.seg[1].A1 = normk16; d.seg[1].W1 = wb[1]; d.seg[1].bias = bk;
  d.seg[1].o16a = k16; d.seg[1].epi = 0;
  d.seg[2] = z; d.seg[2].A1 = normk16; d.seg[2].W1 = wb[2]; d.seg[2].bias = bv_in;
  d.seg[2].o16a = v16; d.seg[2].epi = 0;
  gemm_f<128><<<dim3(32, 24), 256, 0, stream>>>(d);

  // --- Wp (M=512, TN=64, grid 4x16) ---
  d.seg[0] = z; d.seg[0].A1 = pos16; d.seg[0].W1 = wb[3];
  d.seg[0].o16a = r16; d.seg[0].epi = 0;
  gemm_f<64><<<dim3(4, 16), 256, 0, stream>>>(d);

  // --- attention ---
  attn_mfma<<<dim3(8, 16, 8), 256, 0, stream>>>(qu16, qv16, k16, v16, r16, att16);

  // --- Wo (TN=64, grid 32x16) ---
  d.seg[0] = z; d.seg[0].A1 = att16; d.seg[0].W1 = wb[4]; d.seg[0].bias = bo;
  d.seg[0].o16a = Y16; d.seg[0].epi = 0;
  gemm_f<64><<<dim3(32, 16), 256, 0, stream>>>(d);

  // --- gate1 r+z (dual-K, TN=128, grid 32x16) ---
  d.seg[0] = z; d.seg[0].A1 = Y16; d.seg[0].A2 = xq16;
  d.seg[0].W1 = wb[6]; d.seg[0].W2 = wb[7];
  d.seg[0].xF = query; d.seg[0].o16a = rx16; d.seg[0].epi = 3;
  d.seg[1] = z; d.seg[1].A1 = Y16; d.seg[1].A2 = xq16;
  d.seg[1].W1 = wb[8]; d.seg[1].W2 = wb[9];
  d.seg[1].oF = tB; d.seg[1].epi = 2;
  gemm_f<128><<<dim3(32, 16), 256, 0, stream>>>(d);

  // --- gate1 g + combine (dual-K, TN=64, grid 32x16) ---
  d.seg[0] = z; d.seg[0].A1 = Y16; d.seg[0].A2 = rx16;
  d.seg[0].W1 = wb[10]; d.seg[0].W2 = wb[11];
  d.seg[0].xF = query; d.seg[0].zF = tB;
  d.seg[0].oF = out1; d.seg[0].o16a = out116; d.seg[0].epi = 4;
  gemm_f<64><<<dim3(32, 16), 256, 0, stream>>>(d);

  // --- FFN ---
  ln_kernel<<<4096, 256, 0, stream>>>(out1, ln2_g, ln2_b, ln2o16);
  d.seg[0] = z; d.seg[0].A1 = ln2o16; d.seg[0].W1 = wb[5]; d.seg[0].bias = fc_b;
  d.seg[0].o16a = Ef16; d.seg[0].epi = 5;
  gemm_f<64><<<dim3(32, 16), 256, 0, stream>>>(d);

  // --- gate2 r+z (dual-K, TN=128, grid 32x16) ---
  d.seg[0] = z; d.seg[0].A1 = Ef16; d.seg[0].A2 = out116;
  d.seg[0].W1 = wb[12]; d.seg[0].W2 = wb[13];
  d.seg[0].xF = out1; d.seg[0].o16a = rx16; d.seg[0].epi = 3;
  d.seg[1] = z; d.seg[1].A1 = Ef16; d.seg[1].A2 = out116;
  d.seg[1].W1 = wb[14]; d.seg[1].W2 = wb[15];
  d.seg[1].oF = tB; d.seg[1].epi = 2;
  gemm_f<128><<<dim3(32, 16), 256, 0, stream>>>(d);

  // --- gate2 g + final combine (dual-K, TN=64, grid 32x16) ---
  d.seg[0] = z; d.seg[0].A1 = Ef16; d.seg[0].A2 = rx16;
  d.seg[0].W1 = wb[16]; d.seg[0].W2 = wb[17];
  d.seg[0].xF = out1; d.seg[0].zF = tB;
  d.seg[0].oF = (float*)d_out; d.seg[0].epi = 4;
  gemm_f<64><<<dim3(32, 16), 256, 0, stream>>>(d);
}

// Round 4
// 481.389 us; speedup vs baseline: 3.1902x; 1.3046x over previous
//
#include <hip/hip_runtime.h>

typedef unsigned short u16;
typedef __attribute__((ext_vector_type(8))) short short8;
typedef __attribute__((ext_vector_type(4))) float f32x4;

#define DEVFN __device__ __forceinline__

constexpr int Bc = 8, Sc = 512, Ec = 1024, Hc = 16, Dc = 64;

DEVFN u16 f2b(float f) {
  union { float f; unsigned u; } a; a.f = f;
  unsigned u = a.u;
  u += 0x7fffu + ((u >> 16) & 1u);   // RTNE to bf16
  return (u16)(u >> 16);
}
DEVFN unsigned pack2(float a, float b) {
  return (unsigned)f2b(a) | ((unsigned)f2b(b) << 16);
}
DEVFN float wred_sum(float v) {
  #pragma unroll
  for (int o = 32; o; o >>= 1) v += __shfl_xor(v, o, 64);
  return v;
}
DEVFN void gload16(const void* g, void* l) {
  __builtin_amdgcn_global_load_lds(
      (const __attribute__((address_space(1))) void*)g,
      (__attribute__((address_space(3))) void*)l, 16, 0, 0);
}

// ---------------------------------------------------------------------------
// Weight pre-conversion: 18 matrices of 1024x1024 f32 -> bf16
// ---------------------------------------------------------------------------
struct PtrBundle { const float* src[18]; u16* dst[18]; };

__global__ __launch_bounds__(256) void cvtw_kernel(PtrBundle pb)
{
  int w = blockIdx.y;
  int i = blockIdx.x * 256 + threadIdx.x;
  float4 v = ((const float4*)pb.src[w])[i];
  uint2 o; o.x = pack2(v.x, v.y); o.y = pack2(v.z, v.w);
  ((uint2*)pb.dst[w])[i] = o;
}

// ---------------------------------------------------------------------------
// Fused GEMM: C[M,N] = A@W1^T (+ A2@W2^T), A bf16 [M,1024], W bf16 [1024,1024].
// 128xTN tile, BK=32, global_load_lds staging, 4 waves (2x2).
// epi: 0 b16 | 1 qkv-q (two bias variants) | 2 f32 | 3 rx | 4 combine |
//      5 relu | 6 V-transposed scatter (VT[b,h,d,j])
// ---------------------------------------------------------------------------
struct GemmSeg {
  const u16* A1; const u16* A2;      // A2 != null -> dual-K (K=2048)
  const u16* W1; const u16* W2;
  const float* bias;
  const float* bu; const float* bv;  // epi 1
  const float* xF;                   // epi 3/4
  const float* zF;                   // epi 4
  u16* o16a; u16* o16b;
  float* oF;
  int epi;
};
struct GemmDesc { GemmSeg seg[3]; };

template<int TN>
__global__ __launch_bounds__(256) void gemm_f(GemmDesc dd)
{
  constexpr int NI = TN / 32;
  constexpr int BPS = 1024 / TN;
  __shared__ u16 lA[128 * 32];
  __shared__ u16 lB[TN * 32];
  const int tid = threadIdx.x;
  const GemmSeg s = dd.seg[blockIdx.y / BPS];
  const int n0 = (blockIdx.y % BPS) * TN;
  const int m0 = blockIdx.x * 128;
  const int wid = tid >> 6, lane = tid & 63;
  const int wm = (wid >> 1) * 64, wn = (wid & 1) * (TN / 2);
  const int c15 = lane & 15, g8 = (lane >> 4) * 8;
  const int arow = tid >> 2, ac8 = (tid & 3) * 8;

  f32x4 acc[4][NI];
  #pragma unroll
  for (int mi = 0; mi < 4; ++mi)
    #pragma unroll
    for (int ni = 0; ni < NI; ++ni) acc[mi][ni] = {0.f, 0.f, 0.f, 0.f};

  const int nseg = s.A2 ? 2 : 1;
  for (int sg = 0; sg < nseg; ++sg) {
    const u16* Abase = (sg ? s.A2 : s.A1) + (size_t)m0 * 1024;
    const u16* Wbase = (sg ? s.W2 : s.W1) + (size_t)n0 * 1024;
    for (int k0 = 0; k0 < 1024; k0 += 32) {
      gload16(Abase + (size_t)arow * 1024 + k0 + ac8,        &lA[tid * 8]);
      gload16(Abase + (size_t)(arow + 64) * 1024 + k0 + ac8, &lA[2048 + tid * 8]);
      gload16(Wbase + (size_t)arow * 1024 + k0 + ac8,        &lB[tid * 8]);
      if constexpr (TN == 128)
        gload16(Wbase + (size_t)(arow + 64) * 1024 + k0 + ac8, &lB[2048 + tid * 8]);
      __syncthreads();

      short8 afr[4], bfr[NI];
      #pragma unroll
      for (int mi = 0; mi < 4; ++mi)
        afr[mi] = *(const short8*)&lA[(wm + mi * 16 + c15) * 32 + g8];
      #pragma unroll
      for (int ni = 0; ni < NI; ++ni)
        bfr[ni] = *(const short8*)&lB[(wn + ni * 16 + c15) * 32 + g8];
      #pragma unroll
      for (int mi = 0; mi < 4; ++mi)
        #pragma unroll
        for (int ni = 0; ni < NI; ++ni)
          acc[mi][ni] = __builtin_amdgcn_mfma_f32_16x16x32_bf16(
              afr[mi], bfr[ni], acc[mi][ni], 0, 0, 0);
      __syncthreads();
    }
  }

  const int colb = n0 + wn + c15;
  const int rowb = m0 + wm + (lane >> 4) * 4;
  #pragma unroll
  for (int ni = 0; ni < NI; ++ni) {
    int col = colb + ni * 16;
    float bb = s.bias ? s.bias[col] : 0.f;
    float bu = 0.f, bvv = 0.f;
    if (s.epi == 1) { bu = s.bu[col]; bvv = s.bv[col]; }
    #pragma unroll
    for (int mi = 0; mi < 4; ++mi) {
      int row0 = rowb + mi * 16;
      size_t off0 = (size_t)row0 * 1024 + col;
      float v4[4];
      #pragma unroll
      for (int q = 0; q < 4; ++q) v4[q] = acc[mi][ni][q] + bb;
      switch (s.epi) {
        case 0:
          #pragma unroll
          for (int q = 0; q < 4; ++q) s.o16a[off0 + (size_t)q * 1024] = f2b(v4[q]);
          break;
        case 1:
          #pragma unroll
          for (int q = 0; q < 4; ++q) {
            s.o16a[off0 + (size_t)q * 1024] = f2b(v4[q] + bu);
            s.o16b[off0 + (size_t)q * 1024] = f2b(v4[q] + bvv);
          }
          break;
        case 2:
          #pragma unroll
          for (int q = 0; q < 4; ++q) s.oF[off0 + (size_t)q * 1024] = v4[q];
          break;
        case 3:
          #pragma unroll
          for (int q = 0; q < 4; ++q) {
            size_t off = off0 + (size_t)q * 1024;
            float sg1 = 1.f / (1.f + __expf(-v4[q]));
            s.o16a[off] = f2b(sg1 * s.xF[off]);
          }
          break;
        case 4:
          #pragma unroll
          for (int q = 0; q < 4; ++q) {
            size_t off = off0 + (size_t)q * 1024;
            float z = 1.f / (1.f + __expf(-(s.zF[off] - 2.f)));
            float r = (1.f - z) * s.xF[off] + z * tanhf(v4[q]);
            s.oF[off] = r;
            if (s.o16a) s.o16a[off] = f2b(r);
          }
          break;
        case 5:
          #pragma unroll
          for (int q = 0; q < 4; ++q) s.o16a[off0 + (size_t)q * 1024] = f2b(fmaxf(v4[q], 0.f));
          break;
        case 6: {
          // VT[b, h, d, j] <- value at (row=b*512+j, col=h*64+d)
          int bI = row0 >> 9, j = row0 & 511;
          int hI = col >> 6, dI = col & 63;
          uint2 o; o.x = pack2(v4[0], v4[1]); o.y = pack2(v4[2], v4[3]);
          *(uint2*)(s.o16a + (((size_t)(bI * 16 + hI) * 64 + dI) << 9) + j) = o;
        } break;
      }
    }
  }
}

// ---------------------------------------------------------------------------
// LayerNorm over rows of 1024, fp32 in -> bf16 out
// ---------------------------------------------------------------------------
__global__ __launch_bounds__(256) void ln_kernel(
    const float* __restrict__ x, const float* __restrict__ g,
    const float* __restrict__ bb, u16* __restrict__ out)
{
  const int row = blockIdx.x, t = threadIdx.x;
  float4 xv = ((const float4*)x)[(size_t)row * 256 + t];
  float s  = xv.x + xv.y + xv.z + xv.w;
  float s2 = xv.x * xv.x + xv.y * xv.y + xv.z * xv.z + xv.w * xv.w;
  s = wred_sum(s); s2 = wred_sum(s2);
  __shared__ float sh[8];
  int wid = t >> 6, lane = t & 63;
  if (lane == 0) { sh[wid] = s; sh[4 + wid] = s2; }
  __syncthreads();
  s  = sh[0] + sh[1] + sh[2] + sh[3];
  s2 = sh[4] + sh[5] + sh[6] + sh[7];
  float mean = s * (1.f / 1024.f);
  float var  = s2 * (1.f / 1024.f) - mean * mean;
  float rstd = rsqrtf(var + 1e-5f);
  float4 gv = ((const float4*)g)[t];
  float4 bv = ((const float4*)bb)[t];
  uint2 o;
  o.x = pack2((xv.x - mean) * rstd * gv.x + bv.x,
              (xv.y - mean) * rstd * gv.y + bv.y);
  o.y = pack2((xv.z - mean) * rstd * gv.z + bv.z,
              (xv.w - mean) * rstd * gv.w + bv.w);
  *(uint2*)&out[(size_t)row * 1024 + t * 4] = o;
}

__global__ __launch_bounds__(256) void cvt_kernel(
    const float* __restrict__ x, u16* __restrict__ out)
{
  int i = blockIdx.x * 256 + threadIdx.x;
  float4 v = ((const float4*)x)[i];
  uint2 o; o.x = pack2(v.x, v.y); o.y = pack2(v.z, v.w);
  *(uint2*)&out[(size_t)i * 4] = o;
}

__global__ __launch_bounds__(256) void posenc_kernel(u16* __restrict__ out)
{
  int idx = blockIdx.x * 256 + threadIdx.x;   // 0..262143
  int i = idx >> 9, f = idx & 511;
  float pos = (float)(Sc - 1 - i);
  float invf = expf((float)f * -0.017988946039016f);
  float ang = pos * invf;
  out[(size_t)i * 1024 + f]       = f2b(sinf(ang));
  out[(size_t)i * 1024 + 512 + f] = f2b(cosf(ang));
}

// ---------------------------------------------------------------------------
// MFMA flash attention, fused Transformer-XL rel-pos, barrier-free main loop.
// Per wave: 16 q-rows. V read pre-transposed from global (VT[b,h,d,j]).
// Rel-shift via ds_bpermute rotate within 16-lane groups (no LDS, no conflicts).
// Only LDS: per-wave P bf16 transpose buffer (wave-local, no barriers needed).
// ---------------------------------------------------------------------------
__global__ __launch_bounds__(256) void attn_mfma(
    const u16* __restrict__ qu16, const u16* __restrict__ qv16,
    const u16* __restrict__ k16, const u16* __restrict__ vt16,
    const u16* __restrict__ r16, u16* __restrict__ out)
{
  __shared__ u16 PW[4][16 * 72];       // per-wave P bf16, pad 72

  const int tid = threadIdx.x;
  const int wave = tid >> 6, lane = tid & 63;
  const int g = lane >> 4, c15 = lane & 15;
  const int qb = blockIdx.x;           // 0..7
  const int h = blockIdx.y, b = blockIdx.z;
  const int i0w = qb * 64 + wave * 16;

  const size_t bh_off = ((size_t)b * Sc) * Ec + h * Dc;
  const size_t vtbase = ((size_t)(b * Hc + h) * 64) << 9;   // VT row stride 512

  short8 qa[2], va[2];
  #pragma unroll
  for (int kc = 0; kc < 2; ++kc) {
    size_t o = bh_off + (size_t)(i0w + c15) * Ec + kc * 32 + g * 8;
    qa[kc] = *(const short8*)(qu16 + o);
    va[kc] = *(const short8*)(qv16 + o);
  }

  f32x4 oacc[4];
  #pragma unroll
  for (int t = 0; t < 4; ++t) oacc[t] = {0.f, 0.f, 0.f, 0.f};
  float m[4], l[4];
  #pragma unroll
  for (int q = 0; q < 4; ++q) { m[q] = -1e30f; l[q] = 0.f; }

  u16* pw = PW[wave];

  const int NT = qb + 1;
  for (int jt = 0; jt < NT; ++jt) {
    const int j0 = jt * 64;

    // ---- AC = (q+u) K^T  [16 x 64] ----
    f32x4 ac[4];
    #pragma unroll
    for (int t = 0; t < 4; ++t) ac[t] = {0.f, 0.f, 0.f, 0.f};
    #pragma unroll
    for (int kc = 0; kc < 2; ++kc)
      #pragma unroll
      for (int nt = 0; nt < 4; ++nt) {
        size_t o = bh_off + (size_t)(j0 + nt * 16 + c15) * Ec + kc * 32 + g * 8;
        short8 kb = *(const short8*)(k16 + o);
        ac[nt] = __builtin_amdgcn_mfma_f32_16x16x32_bf16(qa[kc], kb, ac[nt], 0, 0, 0);
      }

    // ---- E band = (q+vb) R^T  [16 x 80], tt = 15 - r + c ----
    const int t0 = 496 - i0w + j0;
    f32x4 e5[5];
    #pragma unroll
    for (int t = 0; t < 5; ++t) e5[t] = {0.f, 0.f, 0.f, 0.f};
    #pragma unroll
    for (int kc = 0; kc < 2; ++kc)
      #pragma unroll
      for (int nt = 0; nt < 5; ++nt) {
        int t = t0 + nt * 16 + c15; t = t > 511 ? 511 : t;
        size_t o = (size_t)t * Ec + h * Dc + kc * 32 + g * 8;
        short8 rb = *(const short8*)(r16 + o);
        e5[nt] = __builtin_amdgcn_mfma_f32_16x16x32_bf16(va[kc], rb, e5[nt], 0, 0, 0);
      }

    // ---- rel-shift rotate: rot[nt][q] = E[r=g*4+q][nt*16 + ((15-r+c15)&15)]
    float rot[5][4];
    #pragma unroll
    for (int q = 0; q < 4; ++q) {
      int src = (lane & 48) | ((15 - (g * 4 + q) + c15) & 15);
      #pragma unroll
      for (int nt = 0; nt < 5; ++nt)
        rot[nt][q] = __shfl(e5[nt][q], src, 64);
    }

    // ---- combine + mask ----
    float s[4][4];
    #pragma unroll
    for (int ct = 0; ct < 4; ++ct) {
      int jcol = j0 + ct * 16 + c15;
      #pragma unroll
      for (int q = 0; q < 4; ++q) {
        int r = g * 4 + q;
        int u = 15 - r + c15;
        float bd = (u >> 4) ? rot[ct + 1][q] : rot[ct][q];
        float sv = (ac[ct][q] + bd) * 0.125f;
        s[ct][q] = (jcol <= i0w + r) ? sv : -1e30f;
      }
    }

    // ---- online softmax (rows across lane&15) ----
    float mnew[4], csc[4];
    #pragma unroll
    for (int q = 0; q < 4; ++q) {
      float mx = fmaxf(fmaxf(s[0][q], s[1][q]), fmaxf(s[2][q], s[3][q]));
      #pragma unroll
      for (int o = 8; o; o >>= 1) mx = fmaxf(mx, __shfl_xor(mx, o, 64));
      mnew[q] = fmaxf(m[q], mx);
      csc[q] = __expf(m[q] - mnew[q]);
      m[q] = mnew[q];
    }
    float rs[4] = {0.f, 0.f, 0.f, 0.f};
    float p[4][4];
    #pragma unroll
    for (int ct = 0; ct < 4; ++ct)
      #pragma unroll
      for (int q = 0; q < 4; ++q) {
        p[ct][q] = __expf(s[ct][q] - mnew[q]);
        rs[q] += p[ct][q];
      }
    #pragma unroll
    for (int q = 0; q < 4; ++q) {
      float t = rs[q];
      #pragma unroll
      for (int o = 8; o; o >>= 1) t += __shfl_xor(t, o, 64);
      l[q] = l[q] * csc[q] + t;
      #pragma unroll
      for (int ct = 0; ct < 4; ++ct) oacc[ct][q] *= csc[q];
    }

    // ---- P -> bf16 via per-wave LDS transpose (wave-local, no barrier) ----
    #pragma unroll
    for (int ct = 0; ct < 4; ++ct)
      #pragma unroll
      for (int q = 0; q < 4; ++q)
        pw[(g * 4 + q) * 72 + ct * 16 + c15] = f2b(p[ct][q]);

    // ---- PV: B-fragments straight from global VT ----
    #pragma unroll
    for (int kc = 0; kc < 2; ++kc) {
      short8 pa = *(const short8*)&pw[c15 * 72 + kc * 32 + g * 8];
      #pragma unroll
      for (int nt = 0; nt < 4; ++nt) {
        short8 vb8 = *(const short8*)(vt16 + vtbase +
                        ((size_t)(nt * 16 + c15) << 9) + j0 + kc * 32 + g * 8);
        oacc[nt] = __builtin_amdgcn_mfma_f32_16x16x32_bf16(pa, vb8, oacc[nt], 0, 0, 0);
      }
    }
  }

  #pragma unroll
  for (int q = 0; q < 4; ++q) {
    float rl = 1.f / l[q];
    size_t ro = bh_off + (size_t)(i0w + g * 4 + q) * Ec;
    #pragma unroll
    for (int ct = 0; ct < 4; ++ct)
      out[ro + ct * 16 + c15] = f2b(oacc[ct][q] * rl);
  }
}

// ---------------------------------------------------------------------------
extern "C" void kernel_launch(void* const* d_in, const int* in_sizes, int n_in,
                              void* d_out, int out_size, void* d_ws, size_t ws_size,
                              hipStream_t stream) {
  (void)in_sizes; (void)n_in; (void)out_size; (void)ws_size;

  const float* query = (const float*)d_in[0];
  const float* key   = (const float*)d_in[1];
  const float* ln1_g = (const float*)d_in[4];
  const float* ln1_b = (const float*)d_in[5];
  const float* ln2_g = (const float*)d_in[6];
  const float* ln2_b = (const float*)d_in[7];
  const float* Wq = (const float*)d_in[8];   const float* bq = (const float*)d_in[9];
  const float* Wk = (const float*)d_in[10];  const float* bk = (const float*)d_in[11];
  const float* Wv = (const float*)d_in[12];  const float* bv_in = (const float*)d_in[13];
  const float* Wp = (const float*)d_in[14];
  const float* Wo = (const float*)d_in[15];  const float* bo = (const float*)d_in[16];
  const float* u_bias = (const float*)d_in[17];
  const float* v_bias = (const float*)d_in[18];
  const float* fc_W = (const float*)d_in[31]; const float* fc_b = (const float*)d_in[32];

  const size_t MB = 1ull << 20;
  char* ws = (char*)d_ws;
  u16* wb[18];
  for (int i = 0; i < 18; ++i) wb[i] = (u16*)(ws + (size_t)i * 2 * MB);
  u16*   normq16 = (u16*)(ws + 36 * MB);  // -> att16 -> rx16
  u16*   normk16 = (u16*)(ws + 44 * MB);  // -> Y16
  u16*   xq16    = (u16*)(ws + 52 * MB);  // -> ln2o16
  u16*   pos16   = (u16*)(ws + 60 * MB);
  u16*   r16     = (u16*)(ws + 61 * MB);
  u16*   qu16    = (u16*)(ws + 62 * MB);  // -> out116
  u16*   qv16    = (u16*)(ws + 70 * MB);  // -> Ef16
  u16*   k16     = (u16*)(ws + 78 * MB);  // \ -> tB f32 (16MB)
  u16*   vt16    = (u16*)(ws + 86 * MB);  // /  VT[b,h,d,j]
  float* out1    = (float*)(ws + 94 * MB);// 16MB
  u16*   att16   = normq16;
  u16*   Y16     = normk16;
  u16*   rx16    = normq16;
  u16*   out116  = qu16;
  u16*   Ef16    = qv16;
  u16*   ln2o16  = xq16;
  float* tB      = (float*)k16;

  // --- weight conversion ---
  PtrBundle pb;
  const float* wsrc[18] = {Wq, Wk, Wv, Wp, Wo, fc_W,
                           (const float*)d_in[19], (const float*)d_in[20],
                           (const float*)d_in[21], (const float*)d_in[22],
                           (const float*)d_in[23], (const float*)d_in[24],
                           (const float*)d_in[25], (const float*)d_in[26],
                           (const float*)d_in[27], (const float*)d_in[28],
                           (const float*)d_in[29], (const float*)d_in[30]};
  for (int i = 0; i < 18; ++i) { pb.src[i] = wsrc[i]; pb.dst[i] = wb[i]; }
  cvtw_kernel<<<dim3(1024, 18), 256, 0, stream>>>(pb);

  // --- stage 1 ---
  ln_kernel<<<4096, 256, 0, stream>>>(query, ln1_g, ln1_b, normq16);
  ln_kernel<<<4096, 256, 0, stream>>>(key,   ln1_g, ln1_b, normk16);
  cvt_kernel<<<4096, 256, 0, stream>>>(query, xq16);
  posenc_kernel<<<1024, 256, 0, stream>>>(pos16);

  GemmSeg z{}; GemmDesc d;

  // --- QKV fused (grid 32x24, TN=128); V written transposed (epi 6) ---
  d.seg[0] = z; d.seg[0].A1 = normq16; d.seg[0].W1 = wb[0]; d.seg[0].bias = bq;
  d.seg[0].bu = u_bias; d.seg[0].bv = v_bias;
  d.seg[0].o16a = qu16; d.seg[0].o16b = qv16; d.seg[0].epi = 1;
  d.seg[1] = z; d.seg[1].A1 = normk16; d.seg[1].W1 = wb[1]; d.seg[1].bias = bk;
  d.seg[1].o16a = k16; d.seg[1].epi = 0;
  d.seg[2] = z; d.seg[2].A1 = normk16; d.seg[2].W1 = wb[2]; d.seg[2].bias = bv_in;
  d.seg[2].o16a = vt16; d.seg[2].epi = 6;
  gemm_f<128><<<dim3(32, 24), 256, 0, stream>>>(d);

  // --- Wp (M=512, TN=64, grid 4x16) ---
  d.seg[0] = z; d.seg[0].A1 = pos16; d.seg[0].W1 = wb[3];
  d.seg[0].o16a = r16; d.seg[0].epi = 0;
  gemm_f<64><<<dim3(4, 16), 256, 0, stream>>>(d);

  // --- attention ---
  attn_mfma<<<dim3(8, 16, 8), 256, 0, stream>>>(qu16, qv16, k16, vt16, r16, att16);

  // --- Wo (TN=64, grid 32x16) ---
  d.seg[0] = z; d.seg[0].A1 = att16; d.seg[0].W1 = wb[4]; d.seg[0].bias = bo;
  d.seg[0].o16a = Y16; d.seg[0].epi = 0;
  gemm_f<64><<<dim3(32, 16), 256, 0, stream>>>(d);

  // --- gate1 r+z (dual-K, TN=128, grid 32x16) ---
  d.seg[0] = z; d.seg[0].A1 = Y16; d.seg[0].A2 = xq16;
  d.seg[0].W1 = wb[6]; d.seg[0].W2 = wb[7];
  d.seg[0].xF = query; d.seg[0].o16a = rx16; d.seg[0].epi = 3;
  d.seg[1] = z; d.seg[1].A1 = Y16; d.seg[1].A2 = xq16;
  d.seg[1].W1 = wb[8]; d.seg[1].W2 = wb[9];
  d.seg[1].oF = tB; d.seg[1].epi = 2;
  gemm_f<128><<<dim3(32, 16), 256, 0, stream>>>(d);

  // --- gate1 g + combine (dual-K, TN=64, grid 32x16) ---
  d.seg[0] = z; d.seg[0].A1 = Y16; d.seg[0].A2 = rx16;
  d.seg[0].W1 = wb[10]; d.seg[0].W2 = wb[11];
  d.seg[0].xF = query; d.seg[0].zF = tB;
  d.seg[0].oF = out1; d.seg[0].o16a = out116; d.seg[0].epi = 4;
  gemm_f<64><<<dim3(32, 16), 256, 0, stream>>>(d);

  // --- FFN ---
  ln_kernel<<<4096, 256, 0, stream>>>(out1, ln2_g, ln2_b, ln2o16);
  d.seg[0] = z; d.seg[0].A1 = ln2o16; d.seg[0].W1 = wb[5]; d.seg[0].bias = fc_b;
  d.seg[0].o16a = Ef16; d.seg[0].epi = 5;
  gemm_f<64><<<dim3(32, 16), 256, 0, stream>>>(d);

  // --- gate2 r+z (dual-K, TN=128, grid 32x16) ---
  d.seg[0] = z; d.seg[0].A1 = Ef16; d.seg[0].A2 = out116;
  d.seg[0].W1 = wb[12]; d.seg[0].W2 = wb[13];
  d.seg[0].xF = out1; d.seg[0].o16a = rx16; d.seg[0].epi = 3;
  d.seg[1] = z; d.seg[1].A1 = Ef16; d.seg[1].A2 = out116;
  d.seg[1].W1 = wb[14]; d.seg[1].W2 = wb[15];
  d.seg[1].oF = tB; d.seg[1].epi = 2;
  gemm_f<128><<<dim3(32, 16), 256, 0, stream>>>(d);

  // --- gate2 g + final combine (dual-K, TN=64, grid 32x16) ---
  d.seg[0] = z; d.seg[0].A1 = Ef16; d.seg[0].A2 = rx16;
  d.seg[0].W1 = wb[16]; d.seg[0].W2 = wb[17];
  d.seg[0].xF = out1; d.seg[0].zF = tB;
  d.seg[0].oF = (float*)d_out; d.seg[0].epi = 4;
  gemm_f<64><<<dim3(32, 16), 256, 0, stream>>>(d);
}

// Round 5
// 421.199 us; speedup vs baseline: 3.6461x; 1.1429x over previous
//
#include <hip/hip_runtime.h>

typedef unsigned short u16;
typedef __attribute__((ext_vector_type(8))) short short8;
typedef __attribute__((ext_vector_type(4))) float f32x4;

#define DEVFN __device__ __forceinline__

constexpr int Bc = 8, Sc = 512, Ec = 1024, Hc = 16, Dc = 64;

DEVFN u16 f2b(float f) {
  union { float f; unsigned u; } a; a.f = f;
  unsigned u = a.u;
  u += 0x7fffu + ((u >> 16) & 1u);   // RTNE to bf16
  return (u16)(u >> 16);
}
DEVFN unsigned pack2(float a, float b) {
  return (unsigned)f2b(a) | ((unsigned)f2b(b) << 16);
}
DEVFN float wred_sum(float v) {
  #pragma unroll
  for (int o = 32; o; o >>= 1) v += __shfl_xor(v, o, 64);
  return v;
}
DEVFN void gload16(const void* g, void* l) {
  __builtin_amdgcn_global_load_lds(
      (const __attribute__((address_space(1))) void*)g,
      (__attribute__((address_space(3))) void*)l, 16, 0, 0);
}

// ---------------------------------------------------------------------------
// Weight pre-conversion: 18 matrices of 1024x1024 f32 -> bf16
// ---------------------------------------------------------------------------
struct PtrBundle { const float* src[18]; u16* dst[18]; };

__global__ __launch_bounds__(256) void cvtw_kernel(PtrBundle pb)
{
  int w = blockIdx.y;
  int i = blockIdx.x * 256 + threadIdx.x;
  float4 v = ((const float4*)pb.src[w])[i];
  uint2 o; o.x = pack2(v.x, v.y); o.y = pack2(v.z, v.w);
  ((uint2*)pb.dst[w])[i] = o;
}

// ---------------------------------------------------------------------------
// Fused GEMM: C[M,N] = A@W1^T (+ A2@W2^T), A bf16 [M,1024], W bf16 [1024,1024].
// 128xTN tile, BK=32, global_load_lds staging, 4 waves (2x2).
// epi: 0 b16 row-major | 1 Q-frag (qu,qv scaled 1/8) | 2 f32 | 3 rx |
//      4 combine | 5 relu | 6 VT-frag | 7 K-frag | 8 R-frag
// Fragment layouts (per attention MFMA):
//   K-frag : PK[(b*16+h)*8+kt][ (nt*2+kc)*64 + c15*4 + g ][8]   (8KB/tile)
//   VT-frag: same indexing, nt/c15 index d, kc/g/e index j
//   Q-frag : QF[h][ (i16*2+kc)*64 + c15*4 + g ][8]  i16 = global_row/16
//   R-frag : RF[h][ (t16*2+kc)*64 + c15*4 + g ][8]  t16 = t/16
// ---------------------------------------------------------------------------
struct GemmSeg {
  const u16* A1; const u16* A2;      // A2 != null -> dual-K (K=2048)
  const u16* W1; const u16* W2;
  const float* bias;
  const float* bu; const float* bv;  // epi 1
  const float* xF;                   // epi 3/4
  const float* zF;                   // epi 4
  u16* o16a; u16* o16b;
  float* oF;
  int epi;
};
struct GemmDesc { GemmSeg seg[3]; };

template<int TN>
__global__ __launch_bounds__(256) void gemm_f(GemmDesc dd)
{
  constexpr int NI = TN / 32;
  constexpr int BPS = 1024 / TN;
  __shared__ u16 lA[128 * 32];
  __shared__ u16 lB[TN * 32];
  const int tid = threadIdx.x;
  const GemmSeg s = dd.seg[blockIdx.y / BPS];
  const int n0 = (blockIdx.y % BPS) * TN;
  const int m0 = blockIdx.x * 128;
  const int wid = tid >> 6, lane = tid & 63;
  const int wm = (wid >> 1) * 64, wn = (wid & 1) * (TN / 2);
  const int c15 = lane & 15, g8 = (lane >> 4) * 8;
  const int arow = tid >> 2, ac8 = (tid & 3) * 8;

  f32x4 acc[4][NI];
  #pragma unroll
  for (int mi = 0; mi < 4; ++mi)
    #pragma unroll
    for (int ni = 0; ni < NI; ++ni) acc[mi][ni] = {0.f, 0.f, 0.f, 0.f};

  const int nseg = s.A2 ? 2 : 1;
  for (int sg = 0; sg < nseg; ++sg) {
    const u16* Abase = (sg ? s.A2 : s.A1) + (size_t)m0 * 1024;
    const u16* Wbase = (sg ? s.W2 : s.W1) + (size_t)n0 * 1024;
    for (int k0 = 0; k0 < 1024; k0 += 32) {
      gload16(Abase + (size_t)arow * 1024 + k0 + ac8,        &lA[tid * 8]);
      gload16(Abase + (size_t)(arow + 64) * 1024 + k0 + ac8, &lA[2048 + tid * 8]);
      gload16(Wbase + (size_t)arow * 1024 + k0 + ac8,        &lB[tid * 8]);
      if constexpr (TN == 128)
        gload16(Wbase + (size_t)(arow + 64) * 1024 + k0 + ac8, &lB[2048 + tid * 8]);
      __syncthreads();

      short8 afr[4], bfr[NI];
      #pragma unroll
      for (int mi = 0; mi < 4; ++mi)
        afr[mi] = *(const short8*)&lA[(wm + mi * 16 + c15) * 32 + g8];
      #pragma unroll
      for (int ni = 0; ni < NI; ++ni)
        bfr[ni] = *(const short8*)&lB[(wn + ni * 16 + c15) * 32 + g8];
      #pragma unroll
      for (int mi = 0; mi < 4; ++mi)
        #pragma unroll
        for (int ni = 0; ni < NI; ++ni)
          acc[mi][ni] = __builtin_amdgcn_mfma_f32_16x16x32_bf16(
              afr[mi], bfr[ni], acc[mi][ni], 0, 0, 0);
      __syncthreads();
    }
  }

  const int colb = n0 + wn + c15;
  const int rowb = m0 + wm + (lane >> 4) * 4;
  #pragma unroll
  for (int ni = 0; ni < NI; ++ni) {
    int col = colb + ni * 16;
    float bb = s.bias ? s.bias[col] : 0.f;
    float bu = 0.f, bvv = 0.f;
    if (s.epi == 1) { bu = s.bu[col]; bvv = s.bv[col]; }
    // fragment decompositions of col
    int hI = col >> 6, dI = col & 63;
    int kcd = (dI >> 5) & 1, gd = (dI >> 3) & 3, ed = dI & 7;   // d as k-dim
    int ntd = dI >> 4, c15d = dI & 15;                          // d as row-dim
    #pragma unroll
    for (int mi = 0; mi < 4; ++mi) {
      int row0 = rowb + mi * 16;
      size_t off0 = (size_t)row0 * 1024 + col;
      float v4[4];
      #pragma unroll
      for (int q = 0; q < 4; ++q) v4[q] = acc[mi][ni][q] + bb;
      switch (s.epi) {
        case 0:
          #pragma unroll
          for (int q = 0; q < 4; ++q) s.o16a[off0 + (size_t)q * 1024] = f2b(v4[q]);
          break;
        case 1:
          #pragma unroll
          for (int q = 0; q < 4; ++q) {
            int ri = row0 + q;
            size_t off = ((size_t)hI << 18) +
                         (((size_t)(((ri >> 4) * 2 + kcd) * 16 + (ri & 15)) * 4 + gd) << 3) + ed;
            s.o16a[off] = f2b((v4[q] + bu)  * 0.125f);
            s.o16b[off] = f2b((v4[q] + bvv) * 0.125f);
          }
          break;
        case 2:
          #pragma unroll
          for (int q = 0; q < 4; ++q) s.oF[off0 + (size_t)q * 1024] = v4[q];
          break;
        case 3:
          #pragma unroll
          for (int q = 0; q < 4; ++q) {
            size_t off = off0 + (size_t)q * 1024;
            float sg1 = 1.f / (1.f + __expf(-v4[q]));
            s.o16a[off] = f2b(sg1 * s.xF[off]);
          }
          break;
        case 4:
          #pragma unroll
          for (int q = 0; q < 4; ++q) {
            size_t off = off0 + (size_t)q * 1024;
            float z = 1.f / (1.f + __expf(-(s.zF[off] - 2.f)));
            float r = (1.f - z) * s.xF[off] + z * tanhf(v4[q]);
            s.oF[off] = r;
            if (s.o16a) s.o16a[off] = f2b(r);
          }
          break;
        case 5:
          #pragma unroll
          for (int q = 0; q < 4; ++q) s.o16a[off0 + (size_t)q * 1024] = f2b(fmaxf(v4[q], 0.f));
          break;
        case 6: {
          // VT-frag: row0..row0+3 are consecutive j (same kc/g octet)
          int bI = row0 >> 9, j = row0 & 511;
          int kt = j >> 6, jj = j & 63;
          int kcj = jj >> 5, gj = (jj >> 3) & 3, e0 = jj & 7;
          size_t off = ((size_t)((bI * 16 + hI) * 8 + kt) << 12) +
                       (((size_t)((ntd * 2 + kcj) * 16 + c15d) * 4 + gj) << 3) + e0;
          uint2 o; o.x = pack2(v4[0], v4[1]); o.y = pack2(v4[2], v4[3]);
          *(uint2*)(s.o16a + off) = o;
        } break;
        case 7:
          #pragma unroll
          for (int q = 0; q < 4; ++q) {
            int rj = row0 + q;
            int bI = rj >> 9, kt = (rj >> 6) & 7, jr = rj & 63;
            size_t off = ((size_t)((bI * 16 + hI) * 8 + kt) << 12) +
                         (((size_t)(((jr >> 4) * 2 + kcd) * 16 + (jr & 15)) * 4 + gd) << 3) + ed;
            s.o16a[off] = f2b(v4[q]);
          }
          break;
        case 8:
          #pragma unroll
          for (int q = 0; q < 4; ++q) {
            int t = row0 + q;
            size_t off = ((size_t)hI << 14) +
                         (((size_t)(((t >> 4) * 2 + kcd) * 16 + (t & 15)) * 4 + gd) << 3) + ed;
            s.o16a[off] = f2b(v4[q]);
          }
          break;
      }
    }
  }
}

// ---------------------------------------------------------------------------
// LayerNorm over rows of 1024, fp32 in -> bf16 out
// ---------------------------------------------------------------------------
__global__ __launch_bounds__(256) void ln_kernel(
    const float* __restrict__ x, const float* __restrict__ g,
    const float* __restrict__ bb, u16* __restrict__ out)
{
  const int row = blockIdx.x, t = threadIdx.x;
  float4 xv = ((const float4*)x)[(size_t)row * 256 + t];
  float s  = xv.x + xv.y + xv.z + xv.w;
  float s2 = xv.x * xv.x + xv.y * xv.y + xv.z * xv.z + xv.w * xv.w;
  s = wred_sum(s); s2 = wred_sum(s2);
  __shared__ float sh[8];
  int wid = t >> 6, lane = t & 63;
  if (lane == 0) { sh[wid] = s; sh[4 + wid] = s2; }
  __syncthreads();
  s  = sh[0] + sh[1] + sh[2] + sh[3];
  s2 = sh[4] + sh[5] + sh[6] + sh[7];
  float mean = s * (1.f / 1024.f);
  float var  = s2 * (1.f / 1024.f) - mean * mean;
  float rstd = rsqrtf(var + 1e-5f);
  float4 gv = ((const float4*)g)[t];
  float4 bv = ((const float4*)bb)[t];
  uint2 o;
  o.x = pack2((xv.x - mean) * rstd * gv.x + bv.x,
              (xv.y - mean) * rstd * gv.y + bv.y);
  o.y = pack2((xv.z - mean) * rstd * gv.z + bv.z,
              (xv.w - mean) * rstd * gv.w + bv.w);
  *(uint2*)&out[(size_t)row * 1024 + t * 4] = o;
}

__global__ __launch_bounds__(256) void cvt_kernel(
    const float* __restrict__ x, u16* __restrict__ out)
{
  int i = blockIdx.x * 256 + threadIdx.x;
  float4 v = ((const float4*)x)[i];
  uint2 o; o.x = pack2(v.x, v.y); o.y = pack2(v.z, v.w);
  *(uint2*)&out[(size_t)i * 4] = o;
}

__global__ __launch_bounds__(256) void posenc_kernel(u16* __restrict__ out)
{
  int idx = blockIdx.x * 256 + threadIdx.x;   // 0..262143
  int i = idx >> 9, f = idx & 511;
  float pos = (float)(Sc - 1 - i);
  float invf = expf((float)f * -0.017988946039016f);
  float ang = pos * invf;
  out[(size_t)i * 1024 + f]       = f2b(sinf(ang));
  out[(size_t)i * 1024 + 512 + f] = f2b(cosf(ang));
}

// ---------------------------------------------------------------------------
// MFMA flash attention, balanced q-tile pairing {x, 7-x}, double-buffered
// async LDS staging of fragment-ordered K/VT tiles. qu/qv pre-scaled 1/8.
// ---------------------------------------------------------------------------
__global__ __launch_bounds__(256) void attn_mfma(
    const u16* __restrict__ quF, const u16* __restrict__ qvF,
    const u16* __restrict__ PK, const u16* __restrict__ PVT,
    const u16* __restrict__ RF, u16* __restrict__ out)
{
  __shared__ u16 lK[2][4096];
  __shared__ u16 lVT[2][4096];
  __shared__ u16 PW[4][16 * 72];

  const int tid = threadIdx.x;
  const int wave = tid >> 6, lane = tid & 63;
  const int g = lane >> 4, c15 = lane & 15;
  const int x = blockIdx.x;            // 0..3
  const int h = blockIdx.y, b = blockIdx.z;
  const int qA = x, qB = 7 - x;

  const size_t pkbase = (size_t)(b * 16 + h) << 15;   // 8 tiles * 4096 u16
  const size_t qhead  = (size_t)h << 18;
  const size_t rhead  = (size_t)h << 14;
  const size_t bh_off = ((size_t)b * Sc) * Ec + h * Dc;
  const int fchunk = (c15 * 4 + g) * 8;               // fragment chunk offset

  u16* pw = PW[wave];

  auto stage = [&](int buf, int kt) {
    const u16* ks = PK  + pkbase + ((size_t)kt << 12);
    const u16* vs = PVT + pkbase + ((size_t)kt << 12);
    gload16(ks + tid * 8,        &lK[buf][tid * 8]);
    gload16(ks + 2048 + tid * 8, &lK[buf][2048 + tid * 8]);
    gload16(vs + tid * 8,        &lVT[buf][tid * 8]);
    gload16(vs + 2048 + tid * 8, &lVT[buf][2048 + tid * 8]);
  };

  short8 qa[2], va[2];
  int i0w = qA * 64 + wave * 16;
  {
    int i16g = b * 32 + (i0w >> 4);
    #pragma unroll
    for (int kc = 0; kc < 2; ++kc) {
      size_t off = qhead + ((size_t)(i16g * 2 + kc) * 64) * 8 + fchunk;
      qa[kc] = *(const short8*)(quF + off);
      va[kc] = *(const short8*)(qvF + off);
    }
  }

  f32x4 oacc[4];
  #pragma unroll
  for (int t = 0; t < 4; ++t) oacc[t] = {0.f, 0.f, 0.f, 0.f};
  float m[4], l[4];
  #pragma unroll
  for (int q = 0; q < 4; ++q) { m[q] = -1e30f; l[q] = 0.f; }

  stage(0, 0);
  asm volatile("s_waitcnt vmcnt(0)" ::: "memory");
  __syncthreads();

  for (int s2 = 0; s2 < 9; ++s2) {
    const int buf = s2 & 1;
    const int kt = (s2 <= x) ? s2 : (s2 - x - 1);
    const int j0 = kt * 64;
    if (s2 < 8) {
      int ns = s2 + 1;
      stage(buf ^ 1, (ns <= x) ? ns : (ns - x - 1));
    }

    // ---- AC = (q+u)/8 K^T ----
    f32x4 ac[4];
    #pragma unroll
    for (int t = 0; t < 4; ++t) ac[t] = {0.f, 0.f, 0.f, 0.f};
    __builtin_amdgcn_s_setprio(1);
    #pragma unroll
    for (int kc = 0; kc < 2; ++kc)
      #pragma unroll
      for (int nt = 0; nt < 4; ++nt) {
        short8 kb = *(const short8*)&lK[buf][(nt * 2 + kc) * 512 + fchunk];
        ac[nt] = __builtin_amdgcn_mfma_f32_16x16x32_bf16(qa[kc], kb, ac[nt], 0, 0, 0);
      }

    // ---- E band = (q+vb)/8 R^T ----
    const int t016 = (496 - i0w + j0) >> 4;
    f32x4 e5[5];
    #pragma unroll
    for (int t = 0; t < 5; ++t) e5[t] = {0.f, 0.f, 0.f, 0.f};
    #pragma unroll
    for (int kc = 0; kc < 2; ++kc)
      #pragma unroll
      for (int nt = 0; nt < 5; ++nt) {
        int t16 = t016 + nt; t16 = t16 > 31 ? 31 : t16;
        short8 rb = *(const short8*)(RF + rhead + (size_t)(t16 * 2 + kc) * 512 + fchunk);
        e5[nt] = __builtin_amdgcn_mfma_f32_16x16x32_bf16(va[kc], rb, e5[nt], 0, 0, 0);
      }
    __builtin_amdgcn_s_setprio(0);

    // ---- rel-shift rotate within 16-lane groups ----
    float rot[5][4];
    #pragma unroll
    for (int q = 0; q < 4; ++q) {
      int src = (lane & 48) | ((15 - (g * 4 + q) + c15) & 15);
      #pragma unroll
      for (int nt = 0; nt < 5; ++nt)
        rot[nt][q] = __shfl(e5[nt][q], src, 64);
    }

    // ---- combine + causal mask ----
    float s[4][4];
    #pragma unroll
    for (int ct = 0; ct < 4; ++ct) {
      int jcol = j0 + ct * 16 + c15;
      #pragma unroll
      for (int q = 0; q < 4; ++q) {
        int r = g * 4 + q;
        int u = 15 - r + c15;
        float bd = (u >> 4) ? rot[ct + 1][q] : rot[ct][q];
        float sv = ac[ct][q] + bd;
        s[ct][q] = (jcol <= i0w + r) ? sv : -1e30f;
      }
    }

    // ---- online softmax ----
    float mnew[4], csc[4];
    #pragma unroll
    for (int q = 0; q < 4; ++q) {
      float mx = fmaxf(fmaxf(s[0][q], s[1][q]), fmaxf(s[2][q], s[3][q]));
      #pragma unroll
      for (int o = 8; o; o >>= 1) mx = fmaxf(mx, __shfl_xor(mx, o, 64));
      mnew[q] = fmaxf(m[q], mx);
      csc[q] = __expf(m[q] - mnew[q]);
      m[q] = mnew[q];
    }
    float rs[4] = {0.f, 0.f, 0.f, 0.f};
    float p[4][4];
    #pragma unroll
    for (int ct = 0; ct < 4; ++ct)
      #pragma unroll
      for (int q = 0; q < 4; ++q) {
        p[ct][q] = __expf(s[ct][q] - mnew[q]);
        rs[q] += p[ct][q];
      }
    #pragma unroll
    for (int q = 0; q < 4; ++q) {
      float t = rs[q];
      #pragma unroll
      for (int o = 8; o; o >>= 1) t += __shfl_xor(t, o, 64);
      l[q] = l[q] * csc[q] + t;
      #pragma unroll
      for (int ct = 0; ct < 4; ++ct) oacc[ct][q] *= csc[q];
    }

    // ---- P -> bf16 via per-wave LDS transpose (wave-local) ----
    #pragma unroll
    for (int ct = 0; ct < 4; ++ct)
      #pragma unroll
      for (int q = 0; q < 4; ++q)
        pw[(g * 4 + q) * 72 + ct * 16 + c15] = f2b(p[ct][q]);

    // ---- PV from staged VT ----
    __builtin_amdgcn_s_setprio(1);
    #pragma unroll
    for (int kc = 0; kc < 2; ++kc) {
      short8 pa = *(const short8*)&pw[c15 * 72 + kc * 32 + g * 8];
      #pragma unroll
      for (int nt = 0; nt < 4; ++nt) {
        short8 vb8 = *(const short8*)&lVT[buf][(nt * 2 + kc) * 512 + fchunk];
        oacc[nt] = __builtin_amdgcn_mfma_f32_16x16x32_bf16(pa, vb8, oacc[nt], 0, 0, 0);
      }
    }
    __builtin_amdgcn_s_setprio(0);

    // ---- phase switch: write q-tile A, reset for B ----
    if (s2 == x) {
      #pragma unroll
      for (int q = 0; q < 4; ++q) {
        float rl = 1.f / l[q];
        size_t ro = bh_off + (size_t)(i0w + g * 4 + q) * Ec;
        #pragma unroll
        for (int ct = 0; ct < 4; ++ct)
          out[ro + ct * 16 + c15] = f2b(oacc[ct][q] * rl);
      }
      i0w = qB * 64 + wave * 16;
      int i16g = b * 32 + (i0w >> 4);
      #pragma unroll
      for (int kc = 0; kc < 2; ++kc) {
        size_t off = qhead + ((size_t)(i16g * 2 + kc) * 64) * 8 + fchunk;
        qa[kc] = *(const short8*)(quF + off);
        va[kc] = *(const short8*)(qvF + off);
      }
      #pragma unroll
      for (int t = 0; t < 4; ++t) oacc[t] = {0.f, 0.f, 0.f, 0.f};
      #pragma unroll
      for (int q = 0; q < 4; ++q) { m[q] = -1e30f; l[q] = 0.f; }
    }

    asm volatile("s_waitcnt vmcnt(0)" ::: "memory");
    __syncthreads();
  }

  // ---- write q-tile B ----
  #pragma unroll
  for (int q = 0; q < 4; ++q) {
    float rl = 1.f / l[q];
    size_t ro = bh_off + (size_t)(i0w + g * 4 + q) * Ec;
    #pragma unroll
    for (int ct = 0; ct < 4; ++ct)
      out[ro + ct * 16 + c15] = f2b(oacc[ct][q] * rl);
  }
}

// ---------------------------------------------------------------------------
extern "C" void kernel_launch(void* const* d_in, const int* in_sizes, int n_in,
                              void* d_out, int out_size, void* d_ws, size_t ws_size,
                              hipStream_t stream) {
  (void)in_sizes; (void)n_in; (void)out_size; (void)ws_size;

  const float* query = (const float*)d_in[0];
  const float* key   = (const float*)d_in[1];
  const float* ln1_g = (const float*)d_in[4];
  const float* ln1_b = (const float*)d_in[5];
  const float* ln2_g = (const float*)d_in[6];
  const float* ln2_b = (const float*)d_in[7];
  const float* Wq = (const float*)d_in[8];   const float* bq = (const float*)d_in[9];
  const float* Wk = (const float*)d_in[10];  const float* bk = (const float*)d_in[11];
  const float* Wv = (const float*)d_in[12];  const float* bv_in = (const float*)d_in[13];
  const float* Wp = (const float*)d_in[14];
  const float* Wo = (const float*)d_in[15];  const float* bo = (const float*)d_in[16];
  const float* u_bias = (const float*)d_in[17];
  const float* v_bias = (const float*)d_in[18];
  const float* fc_W = (const float*)d_in[31]; const float* fc_b = (const float*)d_in[32];

  const size_t MB = 1ull << 20;
  char* ws = (char*)d_ws;
  u16* wb[18];
  for (int i = 0; i < 18; ++i) wb[i] = (u16*)(ws + (size_t)i * 2 * MB);
  u16*   normq16 = (u16*)(ws + 36 * MB);  // -> att16 -> rx16
  u16*   normk16 = (u16*)(ws + 44 * MB);  // -> Y16
  u16*   xq16    = (u16*)(ws + 52 * MB);  // -> ln2o16
  u16*   pos16   = (u16*)(ws + 60 * MB);
  u16*   rF16    = (u16*)(ws + 61 * MB);  // R fragment layout (512KB)
  u16*   quF16   = (u16*)(ws + 62 * MB);  // -> out116
  u16*   qvF16   = (u16*)(ws + 70 * MB);  // -> Ef16
  u16*   pk16    = (u16*)(ws + 78 * MB);  // \ -> tB f32 (16MB)
  u16*   pvt16   = (u16*)(ws + 86 * MB);  // /
  float* out1    = (float*)(ws + 94 * MB);// 16MB
  u16*   att16   = normq16;
  u16*   Y16     = normk16;
  u16*   rx16    = normq16;
  u16*   out116  = quF16;
  u16*   Ef16    = qvF16;
  u16*   ln2o16  = xq16;
  float* tB      = (float*)pk16;

  // --- weight conversion ---
  PtrBundle pb;
  const float* wsrc[18] = {Wq, Wk, Wv, Wp, Wo, fc_W,
                           (const float*)d_in[19], (const float*)d_in[20],
                           (const float*)d_in[21], (const float*)d_in[22],
                           (const float*)d_in[23], (const float*)d_in[24],
                           (const float*)d_in[25], (const float*)d_in[26],
                           (const float*)d_in[27], (const float*)d_in[28],
                           (const float*)d_in[29], (const float*)d_in[30]};
  for (int i = 0; i < 18; ++i) { pb.src[i] = wsrc[i]; pb.dst[i] = wb[i]; }
  cvtw_kernel<<<dim3(1024, 18), 256, 0, stream>>>(pb);

  // --- stage 1 ---
  ln_kernel<<<4096, 256, 0, stream>>>(query, ln1_g, ln1_b, normq16);
  ln_kernel<<<4096, 256, 0, stream>>>(key,   ln1_g, ln1_b, normk16);
  cvt_kernel<<<4096, 256, 0, stream>>>(query, xq16);
  posenc_kernel<<<1024, 256, 0, stream>>>(pos16);

  GemmSeg z{}; GemmDesc d;

  // --- QKV fused (grid 32x24, TN=128): Q->frag(1/8), K->frag, V->VT-frag ---
  d.seg[0] = z; d.seg[0].A1 = normq16; d.seg[0].W1 = wb[0]; d.seg[0].bias = bq;
  d.seg[0].bu = u_bias; d.seg[0].bv = v_bias;
  d.seg[0].o16a = quF16; d.seg[0].o16b = qvF16; d.seg[0].epi = 1;
  d.seg[1] = z; d.seg[1].A1 = normk16; d.seg[1].W1 = wb[1]; d.seg[1].bias = bk;
  d.seg[1].o16a = pk16; d.seg[1].epi = 7;
  d.seg[2] = z; d.seg[2].A1 = normk16; d.seg[2].W1 = wb[2]; d.seg[2].bias = bv_in;
  d.seg[2].o16a = pvt16; d.seg[2].epi = 6;
  gemm_f<128><<<dim3(32, 24), 256, 0, stream>>>(d);

  // --- Wp (M=512, TN=64, grid 4x16) -> R fragment layout ---
  d.seg[0] = z; d.seg[0].A1 = pos16; d.seg[0].W1 = wb[3];
  d.seg[0].o16a = rF16; d.seg[0].epi = 8;
  gemm_f<64><<<dim3(4, 16), 256, 0, stream>>>(d);

  // --- attention (balanced pairing, grid 4x16x8) ---
  attn_mfma<<<dim3(4, 16, 8), 256, 0, stream>>>(quF16, qvF16, pk16, pvt16,
                                                rF16, att16);

  // --- Wo (TN=64, grid 32x16) ---
  d.seg[0] = z; d.seg[0].A1 = att16; d.seg[0].W1 = wb[4]; d.seg[0].bias = bo;
  d.seg[0].o16a = Y16; d.seg[0].epi = 0;
  gemm_f<64><<<dim3(32, 16), 256, 0, stream>>>(d);

  // --- gate1 r+z (dual-K, TN=128, grid 32x16) ---
  d.seg[0] = z; d.seg[0].A1 = Y16; d.seg[0].A2 = xq16;
  d.seg[0].W1 = wb[6]; d.seg[0].W2 = wb[7];
  d.seg[0].xF = query; d.seg[0].o16a = rx16; d.seg[0].epi = 3;
  d.seg[1] = z; d.seg[1].A1 = Y16; d.seg[1].A2 = xq16;
  d.seg[1].W1 = wb[8]; d.seg[1].W2 = wb[9];
  d.seg[1].oF = tB; d.seg[1].epi = 2;
  gemm_f<128><<<dim3(32, 16), 256, 0, stream>>>(d);

  // --- gate1 g + combine (dual-K, TN=64, grid 32x16) ---
  d.seg[0] = z; d.seg[0].A1 = Y16; d.seg[0].A2 = rx16;
  d.seg[0].W1 = wb[10]; d.seg[0].W2 = wb[11];
  d.seg[0].xF = query; d.seg[0].zF = tB;
  d.seg[0].oF = out1; d.seg[0].o16a = out116; d.seg[0].epi = 4;
  gemm_f<64><<<dim3(32, 16), 256, 0, stream>>>(d);

  // --- FFN ---
  ln_kernel<<<4096, 256, 0, stream>>>(out1, ln2_g, ln2_b, ln2o16);
  d.seg[0] = z; d.seg[0].A1 = ln2o16; d.seg[0].W1 = wb[5]; d.seg[0].bias = fc_b;
  d.seg[0].o16a = Ef16; d.seg[0].epi = 5;
  gemm_f<64><<<dim3(32, 16), 256, 0, stream>>>(d);

  // --- gate2 r+z (dual-K, TN=128, grid 32x16) ---
  d.seg[0] = z; d.seg[0].A1 = Ef16; d.seg[0].A2 = out116;
  d.seg[0].W1 = wb[12]; d.seg[0].W2 = wb[13];
  d.seg[0].xF = out1; d.seg[0].o16a = rx16; d.seg[0].epi = 3;
  d.seg[1] = z; d.seg[1].A1 = Ef16; d.seg[1].A2 = out116;
  d.seg[1].W1 = wb[14]; d.seg[1].W2 = wb[15];
  d.seg[1].oF = tB; d.seg[1].epi = 2;
  gemm_f<128><<<dim3(32, 16), 256, 0, stream>>>(d);

  // --- gate2 g + final combine (dual-K, TN=64, grid 32x16) ---
  d.seg[0] = z; d.seg[0].A1 = Ef16; d.seg[0].A2 = rx16;
  d.seg[0].W1 = wb[16]; d.seg[0].W2 = wb[17];
  d.seg[0].xF = out1; d.seg[0].zF = tB;
  d.seg[0].oF = (float*)d_out; d.seg[0].epi = 4;
  gemm_f<64><<<dim3(32, 16), 256, 0, stream>>>(d);
}

// Round 6
// 413.043 us; speedup vs baseline: 3.7181x; 1.0197x over previous
//
#include <hip/hip_runtime.h>

typedef unsigned short u16;
typedef __attribute__((ext_vector_type(8))) short short8;
typedef __attribute__((ext_vector_type(4))) float f32x4;

#define DEVFN __device__ __forceinline__

constexpr int Bc = 8, Sc = 512, Ec = 1024, Hc = 16, Dc = 64;

DEVFN u16 f2b(float f) {
  union { float f; unsigned u; } a; a.f = f;
  unsigned u = a.u;
  u += 0x7fffu + ((u >> 16) & 1u);   // RTNE to bf16
  return (u16)(u >> 16);
}
DEVFN unsigned pack2(float a, float b) {
  return (unsigned)f2b(a) | ((unsigned)f2b(b) << 16);
}
DEVFN float wred_sum(float v) {
  #pragma unroll
  for (int o = 32; o; o >>= 1) v += __shfl_xor(v, o, 64);
  return v;
}
DEVFN void gload16(const void* g, void* l) {
  __builtin_amdgcn_global_load_lds(
      (const __attribute__((address_space(1))) void*)g,
      (__attribute__((address_space(3))) void*)l, 16, 0, 0);
}

// ---------------------------------------------------------------------------
// Weight pre-conversion: 18 matrices of 1024x1024 f32 -> bf16
// ---------------------------------------------------------------------------
struct PtrBundle { const float* src[18]; u16* dst[18]; };

__global__ __launch_bounds__(256) void cvtw_kernel(PtrBundle pb)
{
  int w = blockIdx.y;
  int i = blockIdx.x * 256 + threadIdx.x;
  float4 v = ((const float4*)pb.src[w])[i];
  uint2 o; o.x = pack2(v.x, v.y); o.y = pack2(v.z, v.w);
  ((uint2*)pb.dst[w])[i] = o;
}

// ---------------------------------------------------------------------------
// Fused GEMM: C[M,N] = A@W1^T (+ A2@W2^T), A bf16 [M,1024], W bf16 [1024,1024].
// 128xTN tile, BK=32, DOUBLE-BUFFERED global_load_lds staging (prefetch next
// K-step before computing current), 4 waves (2x2).
// epi: 0 b16 row-major | 1 Q-frag (qu,qv scaled 1/8) | 2 f32 | 3 rx |
//      4 combine | 5 relu | 6 VT-frag | 7 K-frag | 8 R-frag
// ---------------------------------------------------------------------------
struct GemmSeg {
  const u16* A1; const u16* A2;      // A2 != null -> dual-K (K=2048)
  const u16* W1; const u16* W2;
  const float* bias;
  const float* bu; const float* bv;  // epi 1
  const float* xF;                   // epi 3/4
  const float* zF;                   // epi 4
  u16* o16a; u16* o16b;
  float* oF;
  int epi;
};
struct GemmDesc { GemmSeg seg[3]; };

template<int TN>
__global__ __launch_bounds__(256) void gemm_f(GemmDesc dd)
{
  constexpr int NI = TN / 32;
  constexpr int BPS = 1024 / TN;
  __shared__ u16 lA[2][128 * 32];
  __shared__ u16 lB[2][TN * 32];
  const int tid = threadIdx.x;
  const GemmSeg s = dd.seg[blockIdx.y / BPS];
  const int n0 = (blockIdx.y % BPS) * TN;
  const int m0 = blockIdx.x * 128;
  const int wid = tid >> 6, lane = tid & 63;
  const int wm = (wid >> 1) * 64, wn = (wid & 1) * (TN / 2);
  const int c15 = lane & 15, g8 = (lane >> 4) * 8;
  const int arow = tid >> 2, ac8 = (tid & 3) * 8;

  f32x4 acc[4][NI];
  #pragma unroll
  for (int mi = 0; mi < 4; ++mi)
    #pragma unroll
    for (int ni = 0; ni < NI; ++ni) acc[mi][ni] = {0.f, 0.f, 0.f, 0.f};

  const int nst = (s.A2 ? 2 : 1) * 32;   // K-steps of 32

  auto stage = [&](int buf, int st) {
    int sg = st >> 5, k0 = (st & 31) << 5;
    const u16* Abase = (sg ? s.A2 : s.A1) + (size_t)m0 * 1024;
    const u16* Wbase = (sg ? s.W2 : s.W1) + (size_t)n0 * 1024;
    gload16(Abase + (size_t)arow * 1024 + k0 + ac8,        &lA[buf][tid * 8]);
    gload16(Abase + (size_t)(arow + 64) * 1024 + k0 + ac8, &lA[buf][2048 + tid * 8]);
    gload16(Wbase + (size_t)arow * 1024 + k0 + ac8,        &lB[buf][tid * 8]);
    if constexpr (TN == 128)
      gload16(Wbase + (size_t)(arow + 64) * 1024 + k0 + ac8, &lB[buf][2048 + tid * 8]);
  };

  stage(0, 0);
  asm volatile("s_waitcnt vmcnt(0)" ::: "memory");
  __syncthreads();

  for (int st = 0; st < nst; ++st) {
    const int cur = st & 1;
    if (st + 1 < nst) stage(cur ^ 1, st + 1);   // prefetch next K-step

    short8 afr[4], bfr[NI];
    #pragma unroll
    for (int mi = 0; mi < 4; ++mi)
      afr[mi] = *(const short8*)&lA[cur][(wm + mi * 16 + c15) * 32 + g8];
    #pragma unroll
    for (int ni = 0; ni < NI; ++ni)
      bfr[ni] = *(const short8*)&lB[cur][(wn + ni * 16 + c15) * 32 + g8];
    #pragma unroll
    for (int mi = 0; mi < 4; ++mi)
      #pragma unroll
      for (int ni = 0; ni < NI; ++ni)
        acc[mi][ni] = __builtin_amdgcn_mfma_f32_16x16x32_bf16(
            afr[mi], bfr[ni], acc[mi][ni], 0, 0, 0);
    __syncthreads();   // drains vmcnt (next buf ready) + lgkm
  }

  const int colb = n0 + wn + c15;
  const int rowb = m0 + wm + (lane >> 4) * 4;
  #pragma unroll
  for (int ni = 0; ni < NI; ++ni) {
    int col = colb + ni * 16;
    float bb = s.bias ? s.bias[col] : 0.f;
    float bu = 0.f, bvv = 0.f;
    if (s.epi == 1) { bu = s.bu[col]; bvv = s.bv[col]; }
    // fragment decompositions of col
    int hI = col >> 6, dI = col & 63;
    int kcd = (dI >> 5) & 1, gd = (dI >> 3) & 3, ed = dI & 7;   // d as k-dim
    int ntd = dI >> 4, c15d = dI & 15;                          // d as row-dim
    #pragma unroll
    for (int mi = 0; mi < 4; ++mi) {
      int row0 = rowb + mi * 16;
      size_t off0 = (size_t)row0 * 1024 + col;
      float v4[4];
      #pragma unroll
      for (int q = 0; q < 4; ++q) v4[q] = acc[mi][ni][q] + bb;
      switch (s.epi) {
        case 0:
          #pragma unroll
          for (int q = 0; q < 4; ++q) s.o16a[off0 + (size_t)q * 1024] = f2b(v4[q]);
          break;
        case 1:
          #pragma unroll
          for (int q = 0; q < 4; ++q) {
            int ri = row0 + q;
            size_t off = ((size_t)hI << 18) +
                         (((size_t)(((ri >> 4) * 2 + kcd) * 16 + (ri & 15)) * 4 + gd) << 3) + ed;
            s.o16a[off] = f2b((v4[q] + bu)  * 0.125f);
            s.o16b[off] = f2b((v4[q] + bvv) * 0.125f);
          }
          break;
        case 2:
          #pragma unroll
          for (int q = 0; q < 4; ++q) s.oF[off0 + (size_t)q * 1024] = v4[q];
          break;
        case 3:
          #pragma unroll
          for (int q = 0; q < 4; ++q) {
            size_t off = off0 + (size_t)q * 1024;
            float sg1 = 1.f / (1.f + __expf(-v4[q]));
            s.o16a[off] = f2b(sg1 * s.xF[off]);
          }
          break;
        case 4:
          #pragma unroll
          for (int q = 0; q < 4; ++q) {
            size_t off = off0 + (size_t)q * 1024;
            float z = 1.f / (1.f + __expf(-(s.zF[off] - 2.f)));
            float r = (1.f - z) * s.xF[off] + z * tanhf(v4[q]);
            s.oF[off] = r;
            if (s.o16a) s.o16a[off] = f2b(r);
          }
          break;
        case 5:
          #pragma unroll
          for (int q = 0; q < 4; ++q) s.o16a[off0 + (size_t)q * 1024] = f2b(fmaxf(v4[q], 0.f));
          break;
        case 6: {
          // VT-frag: row0..row0+3 are consecutive j (same kc/g octet)
          int bI = row0 >> 9, j = row0 & 511;
          int kt = j >> 6, jj = j & 63;
          int kcj = jj >> 5, gj = (jj >> 3) & 3, e0 = jj & 7;
          size_t off = ((size_t)((bI * 16 + hI) * 8 + kt) << 12) +
                       (((size_t)((ntd * 2 + kcj) * 16 + c15d) * 4 + gj) << 3) + e0;
          uint2 o; o.x = pack2(v4[0], v4[1]); o.y = pack2(v4[2], v4[3]);
          *(uint2*)(s.o16a + off) = o;
        } break;
        case 7:
          #pragma unroll
          for (int q = 0; q < 4; ++q) {
            int rj = row0 + q;
            int bI = rj >> 9, kt = (rj >> 6) & 7, jr = rj & 63;
            size_t off = ((size_t)((bI * 16 + hI) * 8 + kt) << 12) +
                         (((size_t)(((jr >> 4) * 2 + kcd) * 16 + (jr & 15)) * 4 + gd) << 3) + ed;
            s.o16a[off] = f2b(v4[q]);
          }
          break;
        case 8:
          #pragma unroll
          for (int q = 0; q < 4; ++q) {
            int t = row0 + q;
            size_t off = ((size_t)hI << 14) +
                         (((size_t)(((t >> 4) * 2 + kcd) * 16 + (t & 15)) * 4 + gd) << 3) + ed;
            s.o16a[off] = f2b(v4[q]);
          }
          break;
      }
    }
  }
}

// ---------------------------------------------------------------------------
// LayerNorm over rows of 1024, fp32 in -> bf16 out (+ optional raw bf16 copy)
// ---------------------------------------------------------------------------
__global__ __launch_bounds__(256) void ln_kernel(
    const float* __restrict__ x, const float* __restrict__ g,
    const float* __restrict__ bb, u16* __restrict__ out,
    u16* __restrict__ out2)
{
  const int row = blockIdx.x, t = threadIdx.x;
  float4 xv = ((const float4*)x)[(size_t)row * 256 + t];
  float s  = xv.x + xv.y + xv.z + xv.w;
  float s2 = xv.x * xv.x + xv.y * xv.y + xv.z * xv.z + xv.w * xv.w;
  s = wred_sum(s); s2 = wred_sum(s2);
  __shared__ float sh[8];
  int wid = t >> 6, lane = t & 63;
  if (lane == 0) { sh[wid] = s; sh[4 + wid] = s2; }
  __syncthreads();
  s  = sh[0] + sh[1] + sh[2] + sh[3];
  s2 = sh[4] + sh[5] + sh[6] + sh[7];
  float mean = s * (1.f / 1024.f);
  float var  = s2 * (1.f / 1024.f) - mean * mean;
  float rstd = rsqrtf(var + 1e-5f);
  float4 gv = ((const float4*)g)[t];
  float4 bv = ((const float4*)bb)[t];
  uint2 o;
  o.x = pack2((xv.x - mean) * rstd * gv.x + bv.x,
              (xv.y - mean) * rstd * gv.y + bv.y);
  o.y = pack2((xv.z - mean) * rstd * gv.z + bv.z,
              (xv.w - mean) * rstd * gv.w + bv.w);
  *(uint2*)&out[(size_t)row * 1024 + t * 4] = o;
  if (out2) {
    uint2 o2; o2.x = pack2(xv.x, xv.y); o2.y = pack2(xv.z, xv.w);
    *(uint2*)&out2[(size_t)row * 1024 + t * 4] = o2;
  }
}

__global__ __launch_bounds__(256) void posenc_kernel(u16* __restrict__ out)
{
  int idx = blockIdx.x * 256 + threadIdx.x;   // 0..262143
  int i = idx >> 9, f = idx & 511;
  float pos = (float)(Sc - 1 - i);
  float invf = expf((float)f * -0.017988946039016f);
  float ang = pos * invf;
  out[(size_t)i * 1024 + f]       = f2b(sinf(ang));
  out[(size_t)i * 1024 + 512 + f] = f2b(cosf(ang));
}

// ---------------------------------------------------------------------------
// MFMA flash attention, balanced q-tile pairing {x, 7-x}, double-buffered
// async LDS staging of fragment-ordered K/VT tiles. qu/qv pre-scaled 1/8.
// ---------------------------------------------------------------------------
__global__ __launch_bounds__(256) void attn_mfma(
    const u16* __restrict__ quF, const u16* __restrict__ qvF,
    const u16* __restrict__ PK, const u16* __restrict__ PVT,
    const u16* __restrict__ RF, u16* __restrict__ out)
{
  __shared__ u16 lK[2][4096];
  __shared__ u16 lVT[2][4096];
  __shared__ u16 PW[4][16 * 72];

  const int tid = threadIdx.x;
  const int wave = tid >> 6, lane = tid & 63;
  const int g = lane >> 4, c15 = lane & 15;
  const int x = blockIdx.x;            // 0..3
  const int h = blockIdx.y, b = blockIdx.z;
  const int qA = x, qB = 7 - x;

  const size_t pkbase = (size_t)(b * 16 + h) << 15;   // 8 tiles * 4096 u16
  const size_t qhead  = (size_t)h << 18;
  const size_t rhead  = (size_t)h << 14;
  const size_t bh_off = ((size_t)b * Sc) * Ec + h * Dc;
  const int fchunk = (c15 * 4 + g) * 8;               // fragment chunk offset

  u16* pw = PW[wave];

  auto stage = [&](int buf, int kt) {
    const u16* ks = PK  + pkbase + ((size_t)kt << 12);
    const u16* vs = PVT + pkbase + ((size_t)kt << 12);
    gload16(ks + tid * 8,        &lK[buf][tid * 8]);
    gload16(ks + 2048 + tid * 8, &lK[buf][2048 + tid * 8]);
    gload16(vs + tid * 8,        &lVT[buf][tid * 8]);
    gload16(vs + 2048 + tid * 8, &lVT[buf][2048 + tid * 8]);
  };

  short8 qa[2], va[2];
  int i0w = qA * 64 + wave * 16;
  {
    int i16g = b * 32 + (i0w >> 4);
    #pragma unroll
    for (int kc = 0; kc < 2; ++kc) {
      size_t off = qhead + ((size_t)(i16g * 2 + kc) * 64) * 8 + fchunk;
      qa[kc] = *(const short8*)(quF + off);
      va[kc] = *(const short8*)(qvF + off);
    }
  }

  f32x4 oacc[4];
  #pragma unroll
  for (int t = 0; t < 4; ++t) oacc[t] = {0.f, 0.f, 0.f, 0.f};
  float m[4], l[4];
  #pragma unroll
  for (int q = 0; q < 4; ++q) { m[q] = -1e30f; l[q] = 0.f; }

  stage(0, 0);
  asm volatile("s_waitcnt vmcnt(0)" ::: "memory");
  __syncthreads();

  for (int s2 = 0; s2 < 9; ++s2) {
    const int buf = s2 & 1;
    const int kt = (s2 <= x) ? s2 : (s2 - x - 1);
    const int j0 = kt * 64;
    if (s2 < 8) {
      int ns = s2 + 1;
      stage(buf ^ 1, (ns <= x) ? ns : (ns - x - 1));
    }

    // ---- AC = (q+u)/8 K^T ----
    f32x4 ac[4];
    #pragma unroll
    for (int t = 0; t < 4; ++t) ac[t] = {0.f, 0.f, 0.f, 0.f};
    __builtin_amdgcn_s_setprio(1);
    #pragma unroll
    for (int kc = 0; kc < 2; ++kc)
      #pragma unroll
      for (int nt = 0; nt < 4; ++nt) {
        short8 kb = *(const short8*)&lK[buf][(nt * 2 + kc) * 512 + fchunk];
        ac[nt] = __builtin_amdgcn_mfma_f32_16x16x32_bf16(qa[kc], kb, ac[nt], 0, 0, 0);
      }

    // ---- E band = (q+vb)/8 R^T ----
    const int t016 = (496 - i0w + j0) >> 4;
    f32x4 e5[5];
    #pragma unroll
    for (int t = 0; t < 5; ++t) e5[t] = {0.f, 0.f, 0.f, 0.f};
    #pragma unroll
    for (int kc = 0; kc < 2; ++kc)
      #pragma unroll
      for (int nt = 0; nt < 5; ++nt) {
        int t16 = t016 + nt; t16 = t16 > 31 ? 31 : t16;
        short8 rb = *(const short8*)(RF + rhead + (size_t)(t16 * 2 + kc) * 512 + fchunk);
        e5[nt] = __builtin_amdgcn_mfma_f32_16x16x32_bf16(va[kc], rb, e5[nt], 0, 0, 0);
      }
    __builtin_amdgcn_s_setprio(0);

    // ---- rel-shift rotate within 16-lane groups ----
    float rot[5][4];
    #pragma unroll
    for (int q = 0; q < 4; ++q) {
      int src = (lane & 48) | ((15 - (g * 4 + q) + c15) & 15);
      #pragma unroll
      for (int nt = 0; nt < 5; ++nt)
        rot[nt][q] = __shfl(e5[nt][q], src, 64);
    }

    // ---- combine + causal mask ----
    float s[4][4];
    #pragma unroll
    for (int ct = 0; ct < 4; ++ct) {
      int jcol = j0 + ct * 16 + c15;
      #pragma unroll
      for (int q = 0; q < 4; ++q) {
        int r = g * 4 + q;
        int u = 15 - r + c15;
        float bd = (u >> 4) ? rot[ct + 1][q] : rot[ct][q];
        float sv = ac[ct][q] + bd;
        s[ct][q] = (jcol <= i0w + r) ? sv : -1e30f;
      }
    }

    // ---- online softmax ----
    float mnew[4], csc[4];
    #pragma unroll
    for (int q = 0; q < 4; ++q) {
      float mx = fmaxf(fmaxf(s[0][q], s[1][q]), fmaxf(s[2][q], s[3][q]));
      #pragma unroll
      for (int o = 8; o; o >>= 1) mx = fmaxf(mx, __shfl_xor(mx, o, 64));
      mnew[q] = fmaxf(m[q], mx);
      csc[q] = __expf(m[q] - mnew[q]);
      m[q] = mnew[q];
    }
    float rs[4] = {0.f, 0.f, 0.f, 0.f};
    float p[4][4];
    #pragma unroll
    for (int ct = 0; ct < 4; ++ct)
      #pragma unroll
      for (int q = 0; q < 4; ++q) {
        p[ct][q] = __expf(s[ct][q] - mnew[q]);
        rs[q] += p[ct][q];
      }
    #pragma unroll
    for (int q = 0; q < 4; ++q) {
      float t = rs[q];
      #pragma unroll
      for (int o = 8; o; o >>= 1) t += __shfl_xor(t, o, 64);
      l[q] = l[q] * csc[q] + t;
      #pragma unroll
      for (int ct = 0; ct < 4; ++ct) oacc[ct][q] *= csc[q];
    }

    // ---- P -> bf16 via per-wave LDS transpose (wave-local) ----
    #pragma unroll
    for (int ct = 0; ct < 4; ++ct)
      #pragma unroll
      for (int q = 0; q < 4; ++q)
        pw[(g * 4 + q) * 72 + ct * 16 + c15] = f2b(p[ct][q]);

    // ---- PV from staged VT ----
    __builtin_amdgcn_s_setprio(1);
    #pragma unroll
    for (int kc = 0; kc < 2; ++kc) {
      short8 pa = *(const short8*)&pw[c15 * 72 + kc * 32 + g * 8];
      #pragma unroll
      for (int nt = 0; nt < 4; ++nt) {
        short8 vb8 = *(const short8*)&lVT[buf][(nt * 2 + kc) * 512 + fchunk];
        oacc[nt] = __builtin_amdgcn_mfma_f32_16x16x32_bf16(pa, vb8, oacc[nt], 0, 0, 0);
      }
    }
    __builtin_amdgcn_s_setprio(0);

    // ---- phase switch: write q-tile A, reset for B ----
    if (s2 == x) {
      #pragma unroll
      for (int q = 0; q < 4; ++q) {
        float rl = 1.f / l[q];
        size_t ro = bh_off + (size_t)(i0w + g * 4 + q) * Ec;
        #pragma unroll
        for (int ct = 0; ct < 4; ++ct)
          out[ro + ct * 16 + c15] = f2b(oacc[ct][q] * rl);
      }
      i0w = qB * 64 + wave * 16;
      int i16g = b * 32 + (i0w >> 4);
      #pragma unroll
      for (int kc = 0; kc < 2; ++kc) {
        size_t off = qhead + ((size_t)(i16g * 2 + kc) * 64) * 8 + fchunk;
        qa[kc] = *(const short8*)(quF + off);
        va[kc] = *(const short8*)(qvF + off);
      }
      #pragma unroll
      for (int t = 0; t < 4; ++t) oacc[t] = {0.f, 0.f, 0.f, 0.f};
      #pragma unroll
      for (int q = 0; q < 4; ++q) { m[q] = -1e30f; l[q] = 0.f; }
    }

    asm volatile("s_waitcnt vmcnt(0)" ::: "memory");
    __syncthreads();
  }

  // ---- write q-tile B ----
  #pragma unroll
  for (int q = 0; q < 4; ++q) {
    float rl = 1.f / l[q];
    size_t ro = bh_off + (size_t)(i0w + g * 4 + q) * Ec;
    #pragma unroll
    for (int ct = 0; ct < 4; ++ct)
      out[ro + ct * 16 + c15] = f2b(oacc[ct][q] * rl);
  }
}

// ---------------------------------------------------------------------------
extern "C" void kernel_launch(void* const* d_in, const int* in_sizes, int n_in,
                              void* d_out, int out_size, void* d_ws, size_t ws_size,
                              hipStream_t stream) {
  (void)in_sizes; (void)n_in; (void)out_size; (void)ws_size;

  const float* query = (const float*)d_in[0];
  const float* key   = (const float*)d_in[1];
  const float* ln1_g = (const float*)d_in[4];
  const float* ln1_b = (const float*)d_in[5];
  const float* ln2_g = (const float*)d_in[6];
  const float* ln2_b = (const float*)d_in[7];
  const float* Wq = (const float*)d_in[8];   const float* bq = (const float*)d_in[9];
  const float* Wk = (const float*)d_in[10];  const float* bk = (const float*)d_in[11];
  const float* Wv = (const float*)d_in[12];  const float* bv_in = (const float*)d_in[13];
  const float* Wp = (const float*)d_in[14];
  const float* Wo = (const float*)d_in[15];  const float* bo = (const float*)d_in[16];
  const float* u_bias = (const float*)d_in[17];
  const float* v_bias = (const float*)d_in[18];
  const float* fc_W = (const float*)d_in[31]; const float* fc_b = (const float*)d_in[32];

  const size_t MB = 1ull << 20;
  char* ws = (char*)d_ws;
  u16* wb[18];
  for (int i = 0; i < 18; ++i) wb[i] = (u16*)(ws + (size_t)i * 2 * MB);
  u16*   normq16 = (u16*)(ws + 36 * MB);  // -> att16 -> rx16
  u16*   normk16 = (u16*)(ws + 44 * MB);  // -> Y16
  u16*   xq16    = (u16*)(ws + 52 * MB);  // -> ln2o16
  u16*   pos16   = (u16*)(ws + 60 * MB);
  u16*   rF16    = (u16*)(ws + 61 * MB);  // R fragment layout (512KB)
  u16*   quF16   = (u16*)(ws + 62 * MB);  // -> out116
  u16*   qvF16   = (u16*)(ws + 70 * MB);  // -> Ef16
  u16*   pk16    = (u16*)(ws + 78 * MB);  // \ -> tB f32 (16MB)
  u16*   pvt16   = (u16*)(ws + 86 * MB);  // /
  float* out1    = (float*)(ws + 94 * MB);// 16MB
  u16*   att16   = normq16;
  u16*   Y16     = normk16;
  u16*   rx16    = normq16;
  u16*   out116  = quF16;
  u16*   Ef16    = qvF16;
  u16*   ln2o16  = xq16;
  float* tB      = (float*)pk16;

  // --- weight conversion ---
  PtrBundle pb;
  const float* wsrc[18] = {Wq, Wk, Wv, Wp, Wo, fc_W,
                           (const float*)d_in[19], (const float*)d_in[20],
                           (const float*)d_in[21], (const float*)d_in[22],
                           (const float*)d_in[23], (const float*)d_in[24],
                           (const float*)d_in[25], (const float*)d_in[26],
                           (const float*)d_in[27], (const float*)d_in[28],
                           (const float*)d_in[29], (const float*)d_in[30]};
  for (int i = 0; i < 18; ++i) { pb.src[i] = wsrc[i]; pb.dst[i] = wb[i]; }
  cvtw_kernel<<<dim3(1024, 18), 256, 0, stream>>>(pb);

  // --- stage 1 (query LN also emits raw bf16 copy -> xq16) ---
  ln_kernel<<<4096, 256, 0, stream>>>(query, ln1_g, ln1_b, normq16, xq16);
  ln_kernel<<<4096, 256, 0, stream>>>(key,   ln1_g, ln1_b, normk16, nullptr);
  posenc_kernel<<<1024, 256, 0, stream>>>(pos16);

  GemmSeg z{}; GemmDesc d;

  // --- QKV fused (grid 32x24, TN=128): Q->frag(1/8), K->frag, V->VT-frag ---
  d.seg[0] = z; d.seg[0].A1 = normq16; d.seg[0].W1 = wb[0]; d.seg[0].bias = bq;
  d.seg[0].bu = u_bias; d.seg[0].bv = v_bias;
  d.seg[0].o16a = quF16; d.seg[0].o16b = qvF16; d.seg[0].epi = 1;
  d.seg[1] = z; d.seg[1].A1 = normk16; d.seg[1].W1 = wb[1]; d.seg[1].bias = bk;
  d.seg[1].o16a = pk16; d.seg[1].epi = 7;
  d.seg[2] = z; d.seg[2].A1 = normk16; d.seg[2].W1 = wb[2]; d.seg[2].bias = bv_in;
  d.seg[2].o16a = pvt16; d.seg[2].epi = 6;
  gemm_f<128><<<dim3(32, 24), 256, 0, stream>>>(d);

  // --- Wp (M=512, TN=64, grid 4x16) -> R fragment layout ---
  d.seg[0] = z; d.seg[0].A1 = pos16; d.seg[0].W1 = wb[3];
  d.seg[0].o16a = rF16; d.seg[0].epi = 8;
  gemm_f<64><<<dim3(4, 16), 256, 0, stream>>>(d);

  // --- attention (balanced pairing, grid 4x16x8) ---
  attn_mfma<<<dim3(4, 16, 8), 256, 0, stream>>>(quF16, qvF16, pk16, pvt16,
                                                rF16, att16);

  // --- Wo (TN=64, grid 32x16) ---
  d.seg[0] = z; d.seg[0].A1 = att16; d.seg[0].W1 = wb[4]; d.seg[0].bias = bo;
  d.seg[0].o16a = Y16; d.seg[0].epi = 0;
  gemm_f<64><<<dim3(32, 16), 256, 0, stream>>>(d);

  // --- gate1 r+z (dual-K, TN=128, grid 32x16) ---
  d.seg[0] = z; d.seg[0].A1 = Y16; d.seg[0].A2 = xq16;
  d.seg[0].W1 = wb[6]; d.seg[0].W2 = wb[7];
  d.seg[0].xF = query; d.seg[0].o16a = rx16; d.seg[0].epi = 3;
  d.seg[1] = z; d.seg[1].A1 = Y16; d.seg[1].A2 = xq16;
  d.seg[1].W1 = wb[8]; d.seg[1].W2 = wb[9];
  d.seg[1].oF = tB; d.seg[1].epi = 2;
  gemm_f<128><<<dim3(32, 16), 256, 0, stream>>>(d);

  // --- gate1 g + combine (dual-K, TN=64, grid 32x16) ---
  d.seg[0] = z; d.seg[0].A1 = Y16; d.seg[0].A2 = rx16;
  d.seg[0].W1 = wb[10]; d.seg[0].W2 = wb[11];
  d.seg[0].xF = query; d.seg[0].zF = tB;
  d.seg[0].oF = out1; d.seg[0].o16a = out116; d.seg[0].epi = 4;
  gemm_f<64><<<dim3(32, 16), 256, 0, stream>>>(d);

  // --- FFN ---
  ln_kernel<<<4096, 256, 0, stream>>>(out1, ln2_g, ln2_b, ln2o16, nullptr);
  d.seg[0] = z; d.seg[0].A1 = ln2o16; d.seg[0].W1 = wb[5]; d.seg[0].bias = fc_b;
  d.seg[0].o16a = Ef16; d.seg[0].epi = 5;
  gemm_f<64><<<dim3(32, 16), 256, 0, stream>>>(d);

  // --- gate2 r+z (dual-K, TN=128, grid 32x16) ---
  d.seg[0] = z; d.seg[0].A1 = Ef16; d.seg[0].A2 = out116;
  d.seg[0].W1 = wb[12]; d.seg[0].W2 = wb[13];
  d.seg[0].xF = out1; d.seg[0].o16a = rx16; d.seg[0].epi = 3;
  d.seg[1] = z; d.seg[1].A1 = Ef16; d.seg[1].A2 = out116;
  d.seg[1].W1 = wb[14]; d.seg[1].W2 = wb[15];
  d.seg[1].oF = tB; d.seg[1].epi = 2;
  gemm_f<128><<<dim3(32, 16), 256, 0, stream>>>(d);

  // --- gate2 g + final combine (dual-K, TN=64, grid 32x16) ---
  d.seg[0] = z; d.seg[0].A1 = Ef16; d.seg[0].A2 = rx16;
  d.seg[0].W1 = wb[16]; d.seg[0].W2 = wb[17];
  d.seg[0].xF = out1; d.seg[0].zF = tB;
  d.seg[0].oF = (float*)d_out; d.seg[0].epi = 4;
  gemm_f<64><<<dim3(32, 16), 256, 0, stream>>>(d);
}

// Round 7
// 390.448 us; speedup vs baseline: 3.9332x; 1.0579x over previous
//
#include <hip/hip_runtime.h>

typedef unsigned short u16;
typedef __attribute__((ext_vector_type(8))) short short8;
typedef __attribute__((ext_vector_type(4))) float f32x4;

#define DEVFN __device__ __forceinline__

constexpr int Bc = 8, Sc = 512, Ec = 1024, Hc = 16, Dc = 64;

DEVFN u16 f2b(float f) {
  union { float f; unsigned u; } a; a.f = f;
  unsigned u = a.u;
  u += 0x7fffu + ((u >> 16) & 1u);   // RTNE to bf16
  return (u16)(u >> 16);
}
DEVFN unsigned pack2(float a, float b) {
  return (unsigned)f2b(a) | ((unsigned)f2b(b) << 16);
}
DEVFN float wred_sum(float v) {
  #pragma unroll
  for (int o = 32; o; o >>= 1) v += __shfl_xor(v, o, 64);
  return v;
}
DEVFN void gload16(const void* g, void* l) {
  __builtin_amdgcn_global_load_lds(
      (const __attribute__((address_space(1))) void*)g,
      (__attribute__((address_space(3))) void*)l, 16, 0, 0);
}

// ---------------------------------------------------------------------------
// Weight pre-conversion: 18 matrices of 1024x1024 f32 -> bf16
// ---------------------------------------------------------------------------
struct PtrBundle { const float* src[18]; u16* dst[18]; };

__global__ __launch_bounds__(256) void cvtw_kernel(PtrBundle pb)
{
  int w = blockIdx.y;
  int i = blockIdx.x * 256 + threadIdx.x;
  float4 v = ((const float4*)pb.src[w])[i];
  uint2 o; o.x = pack2(v.x, v.y); o.y = pack2(v.z, v.w);
  ((uint2*)pb.dst[w])[i] = o;
}

// ---------------------------------------------------------------------------
// Fused GEMM: C[M,N] = A@W1^T (+ A2@W2^T), A bf16 [M,1024], W bf16 [1024,1024].
// 128xTN tile, BK=32, double-buffered global_load_lds staging with COUNTED
// vmcnt (next tile's loads stay in flight across the barrier — T3/T4 minimum),
// 4 waves (2x2).
// epi: 0 b16 row-major | 1 Q-frag (qu,qv scaled 1/8) | 2 f32 | 3 rx |
//      4 combine | 5 relu | 6 VT-frag | 7 K-frag | 8 R-frag
// ---------------------------------------------------------------------------
struct GemmSeg {
  const u16* A1; const u16* A2;      // A2 != null -> dual-K (K=2048)
  const u16* W1; const u16* W2;
  const float* bias;
  const float* bu; const float* bv;  // epi 1
  const float* xF;                   // epi 3/4
  const float* zF;                   // epi 4
  u16* o16a; u16* o16b;
  float* oF;
  int epi;
};
struct GemmDesc { GemmSeg seg[3]; };

template<int TN>
__global__ __launch_bounds__(256) void gemm_f(GemmDesc dd)
{
  constexpr int NI = TN / 32;
  constexpr int BPS = 1024 / TN;
  __shared__ u16 lA[2][128 * 32];
  __shared__ u16 lB[2][TN * 32];
  const int tid = threadIdx.x;
  const GemmSeg s = dd.seg[blockIdx.y / BPS];
  const int n0 = (blockIdx.y % BPS) * TN;
  const int m0 = blockIdx.x * 128;
  const int wid = tid >> 6, lane = tid & 63;
  const int wm = (wid >> 1) * 64, wn = (wid & 1) * (TN / 2);
  const int c15 = lane & 15, g8 = (lane >> 4) * 8;
  const int arow = tid >> 2, ac8 = (tid & 3) * 8;

  f32x4 acc[4][NI];
  #pragma unroll
  for (int mi = 0; mi < 4; ++mi)
    #pragma unroll
    for (int ni = 0; ni < NI; ++ni) acc[mi][ni] = {0.f, 0.f, 0.f, 0.f};

  const int nst = (s.A2 ? 2 : 1) * 32;   // K-steps of 32

  auto stage = [&](int buf, int st) {
    int sg = st >> 5, k0 = (st & 31) << 5;
    const u16* Abase = (sg ? s.A2 : s.A1) + (size_t)m0 * 1024;
    const u16* Wbase = (sg ? s.W2 : s.W1) + (size_t)n0 * 1024;
    gload16(Abase + (size_t)arow * 1024 + k0 + ac8,        &lA[buf][tid * 8]);
    gload16(Abase + (size_t)(arow + 64) * 1024 + k0 + ac8, &lA[buf][2048 + tid * 8]);
    gload16(Wbase + (size_t)arow * 1024 + k0 + ac8,        &lB[buf][tid * 8]);
    if constexpr (TN == 128)
      gload16(Wbase + (size_t)(arow + 64) * 1024 + k0 + ac8, &lB[buf][2048 + tid * 8]);
  };

  // prologue: tiles 0 and 1 in flight
  stage(0, 0);
  stage(1, 1);

  for (int st = 0; st < nst; ++st) {
    const int cur = st & 1;
    // wait for tile st's loads only; tile st+1's stay in flight
    if (st + 1 < nst) {
      if constexpr (TN == 128) asm volatile("s_waitcnt vmcnt(4)" ::: "memory");
      else                     asm volatile("s_waitcnt vmcnt(3)" ::: "memory");
    } else {
      asm volatile("s_waitcnt vmcnt(0)" ::: "memory");
    }
    __builtin_amdgcn_s_barrier();

    short8 afr[4], bfr[NI];
    #pragma unroll
    for (int mi = 0; mi < 4; ++mi)
      afr[mi] = *(const short8*)&lA[cur][(wm + mi * 16 + c15) * 32 + g8];
    #pragma unroll
    for (int ni = 0; ni < NI; ++ni)
      bfr[ni] = *(const short8*)&lB[cur][(wn + ni * 16 + c15) * 32 + g8];
    asm volatile("s_waitcnt lgkmcnt(0)" ::: "memory");
    __builtin_amdgcn_sched_barrier(0);
    __builtin_amdgcn_s_barrier();          // all waves done reading buf[cur]
    __builtin_amdgcn_sched_barrier(0);
    if (st + 2 < nst) stage(cur, st + 2);  // overwrite safe; hides under MFMAs

    #pragma unroll
    for (int mi = 0; mi < 4; ++mi)
      #pragma unroll
      for (int ni = 0; ni < NI; ++ni)
        acc[mi][ni] = __builtin_amdgcn_mfma_f32_16x16x32_bf16(
            afr[mi], bfr[ni], acc[mi][ni], 0, 0, 0);
  }

  const int colb = n0 + wn + c15;
  const int rowb = m0 + wm + (lane >> 4) * 4;
  #pragma unroll
  for (int ni = 0; ni < NI; ++ni) {
    int col = colb + ni * 16;
    float bb = s.bias ? s.bias[col] : 0.f;
    float bu = 0.f, bvv = 0.f;
    if (s.epi == 1) { bu = s.bu[col]; bvv = s.bv[col]; }
    // fragment decompositions of col
    int hI = col >> 6, dI = col & 63;
    int kcd = (dI >> 5) & 1, gd = (dI >> 3) & 3, ed = dI & 7;   // d as k-dim
    int ntd = dI >> 4, c15d = dI & 15;                          // d as row-dim
    #pragma unroll
    for (int mi = 0; mi < 4; ++mi) {
      int row0 = rowb + mi * 16;
      size_t off0 = (size_t)row0 * 1024 + col;
      float v4[4];
      #pragma unroll
      for (int q = 0; q < 4; ++q) v4[q] = acc[mi][ni][q] + bb;
      switch (s.epi) {
        case 0:
          #pragma unroll
          for (int q = 0; q < 4; ++q) s.o16a[off0 + (size_t)q * 1024] = f2b(v4[q]);
          break;
        case 1:
          #pragma unroll
          for (int q = 0; q < 4; ++q) {
            int ri = row0 + q;
            size_t off = ((size_t)hI << 18) +
                         (((size_t)(((ri >> 4) * 2 + kcd) * 16 + (ri & 15)) * 4 + gd) << 3) + ed;
            s.o16a[off] = f2b((v4[q] + bu)  * 0.125f);
            s.o16b[off] = f2b((v4[q] + bvv) * 0.125f);
          }
          break;
        case 2:
          #pragma unroll
          for (int q = 0; q < 4; ++q) s.oF[off0 + (size_t)q * 1024] = v4[q];
          break;
        case 3:
          #pragma unroll
          for (int q = 0; q < 4; ++q) {
            size_t off = off0 + (size_t)q * 1024;
            float sg1 = 1.f / (1.f + __expf(-v4[q]));
            s.o16a[off] = f2b(sg1 * s.xF[off]);
          }
          break;
        case 4:
          #pragma unroll
          for (int q = 0; q < 4; ++q) {
            size_t off = off0 + (size_t)q * 1024;
            float z = 1.f / (1.f + __expf(-(s.zF[off] - 2.f)));
            float r = (1.f - z) * s.xF[off] + z * tanhf(v4[q]);
            s.oF[off] = r;
            if (s.o16a) s.o16a[off] = f2b(r);
          }
          break;
        case 5:
          #pragma unroll
          for (int q = 0; q < 4; ++q) s.o16a[off0 + (size_t)q * 1024] = f2b(fmaxf(v4[q], 0.f));
          break;
        case 6: {
          // VT-frag: row0..row0+3 are consecutive j (same kc/g octet)
          int bI = row0 >> 9, j = row0 & 511;
          int kt = j >> 6, jj = j & 63;
          int kcj = jj >> 5, gj = (jj >> 3) & 3, e0 = jj & 7;
          size_t off = ((size_t)((bI * 16 + hI) * 8 + kt) << 12) +
                       (((size_t)((ntd * 2 + kcj) * 16 + c15d) * 4 + gj) << 3) + e0;
          uint2 o; o.x = pack2(v4[0], v4[1]); o.y = pack2(v4[2], v4[3]);
          *(uint2*)(s.o16a + off) = o;
        } break;
        case 7:
          #pragma unroll
          for (int q = 0; q < 4; ++q) {
            int rj = row0 + q;
            int bI = rj >> 9, kt = (rj >> 6) & 7, jr = rj & 63;
            size_t off = ((size_t)((bI * 16 + hI) * 8 + kt) << 12) +
                         (((size_t)(((jr >> 4) * 2 + kcd) * 16 + (jr & 15)) * 4 + gd) << 3) + ed;
            s.o16a[off] = f2b(v4[q]);
          }
          break;
        case 8:
          #pragma unroll
          for (int q = 0; q < 4; ++q) {
            int t = row0 + q;
            size_t off = ((size_t)hI << 14) +
                         (((size_t)(((t >> 4) * 2 + kcd) * 16 + (t & 15)) * 4 + gd) << 3) + ed;
            s.o16a[off] = f2b(v4[q]);
          }
          break;
      }
    }
  }
}

// ---------------------------------------------------------------------------
// LayerNorm over rows of 1024, fp32 in -> bf16 out (+ optional raw bf16 copy)
// ---------------------------------------------------------------------------
__global__ __launch_bounds__(256) void ln_kernel(
    const float* __restrict__ x, const float* __restrict__ g,
    const float* __restrict__ bb, u16* __restrict__ out,
    u16* __restrict__ out2)
{
  const int row = blockIdx.x, t = threadIdx.x;
  float4 xv = ((const float4*)x)[(size_t)row * 256 + t];
  float s  = xv.x + xv.y + xv.z + xv.w;
  float s2 = xv.x * xv.x + xv.y * xv.y + xv.z * xv.z + xv.w * xv.w;
  s = wred_sum(s); s2 = wred_sum(s2);
  __shared__ float sh[8];
  int wid = t >> 6, lane = t & 63;
  if (lane == 0) { sh[wid] = s; sh[4 + wid] = s2; }
  __syncthreads();
  s  = sh[0] + sh[1] + sh[2] + sh[3];
  s2 = sh[4] + sh[5] + sh[6] + sh[7];
  float mean = s * (1.f / 1024.f);
  float var  = s2 * (1.f / 1024.f) - mean * mean;
  float rstd = rsqrtf(var + 1e-5f);
  float4 gv = ((const float4*)g)[t];
  float4 bv = ((const float4*)bb)[t];
  uint2 o;
  o.x = pack2((xv.x - mean) * rstd * gv.x + bv.x,
              (xv.y - mean) * rstd * gv.y + bv.y);
  o.y = pack2((xv.z - mean) * rstd * gv.z + bv.z,
              (xv.w - mean) * rstd * gv.w + bv.w);
  *(uint2*)&out[(size_t)row * 1024 + t * 4] = o;
  if (out2) {
    uint2 o2; o2.x = pack2(xv.x, xv.y); o2.y = pack2(xv.z, xv.w);
    *(uint2*)&out2[(size_t)row * 1024 + t * 4] = o2;
  }
}

__global__ __launch_bounds__(256) void posenc_kernel(u16* __restrict__ out)
{
  int idx = blockIdx.x * 256 + threadIdx.x;   // 0..262143
  int i = idx >> 9, f = idx & 511;
  float pos = (float)(Sc - 1 - i);
  float invf = expf((float)f * -0.017988946039016f);
  float ang = pos * invf;
  out[(size_t)i * 1024 + f]       = f2b(sinf(ang));
  out[(size_t)i * 1024 + 512 + f] = f2b(cosf(ang));
}

// ---------------------------------------------------------------------------
// MFMA flash attention, balanced q-tile pairing {x, 7-x}, double-buffered
// async LDS staging of fragment-ordered K/VT tiles. qu/qv pre-scaled 1/8.
// ---------------------------------------------------------------------------
__global__ __launch_bounds__(256) void attn_mfma(
    const u16* __restrict__ quF, const u16* __restrict__ qvF,
    const u16* __restrict__ PK, const u16* __restrict__ PVT,
    const u16* __restrict__ RF, u16* __restrict__ out)
{
  __shared__ u16 lK[2][4096];
  __shared__ u16 lVT[2][4096];
  __shared__ u16 PW[4][16 * 72];

  const int tid = threadIdx.x;
  const int wave = tid >> 6, lane = tid & 63;
  const int g = lane >> 4, c15 = lane & 15;
  const int x = blockIdx.x;            // 0..3
  const int h = blockIdx.y, b = blockIdx.z;
  const int qA = x, qB = 7 - x;

  const size_t pkbase = (size_t)(b * 16 + h) << 15;   // 8 tiles * 4096 u16
  const size_t qhead  = (size_t)h << 18;
  const size_t rhead  = (size_t)h << 14;
  const size_t bh_off = ((size_t)b * Sc) * Ec + h * Dc;
  const int fchunk = (c15 * 4 + g) * 8;               // fragment chunk offset

  u16* pw = PW[wave];

  auto stage = [&](int buf, int kt) {
    const u16* ks = PK  + pkbase + ((size_t)kt << 12);
    const u16* vs = PVT + pkbase + ((size_t)kt << 12);
    gload16(ks + tid * 8,        &lK[buf][tid * 8]);
    gload16(ks + 2048 + tid * 8, &lK[buf][2048 + tid * 8]);
    gload16(vs + tid * 8,        &lVT[buf][tid * 8]);
    gload16(vs + 2048 + tid * 8, &lVT[buf][2048 + tid * 8]);
  };

  short8 qa[2], va[2];
  int i0w = qA * 64 + wave * 16;
  {
    int i16g = b * 32 + (i0w >> 4);
    #pragma unroll
    for (int kc = 0; kc < 2; ++kc) {
      size_t off = qhead + ((size_t)(i16g * 2 + kc) * 64) * 8 + fchunk;
      qa[kc] = *(const short8*)(quF + off);
      va[kc] = *(const short8*)(qvF + off);
    }
  }

  f32x4 oacc[4];
  #pragma unroll
  for (int t = 0; t < 4; ++t) oacc[t] = {0.f, 0.f, 0.f, 0.f};
  float m[4], l[4];
  #pragma unroll
  for (int q = 0; q < 4; ++q) { m[q] = -1e30f; l[q] = 0.f; }

  stage(0, 0);
  asm volatile("s_waitcnt vmcnt(0)" ::: "memory");
  __syncthreads();

  for (int s2 = 0; s2 < 9; ++s2) {
    const int buf = s2 & 1;
    const int kt = (s2 <= x) ? s2 : (s2 - x - 1);
    const int j0 = kt * 64;
    if (s2 < 8) {
      int ns = s2 + 1;
      stage(buf ^ 1, (ns <= x) ? ns : (ns - x - 1));
    }

    // ---- AC = (q+u)/8 K^T ----
    f32x4 ac[4];
    #pragma unroll
    for (int t = 0; t < 4; ++t) ac[t] = {0.f, 0.f, 0.f, 0.f};
    __builtin_amdgcn_s_setprio(1);
    #pragma unroll
    for (int kc = 0; kc < 2; ++kc)
      #pragma unroll
      for (int nt = 0; nt < 4; ++nt) {
        short8 kb = *(const short8*)&lK[buf][(nt * 2 + kc) * 512 + fchunk];
        ac[nt] = __builtin_amdgcn_mfma_f32_16x16x32_bf16(qa[kc], kb, ac[nt], 0, 0, 0);
      }

    // ---- E band = (q+vb)/8 R^T ----
    const int t016 = (496 - i0w + j0) >> 4;
    f32x4 e5[5];
    #pragma unroll
    for (int t = 0; t < 5; ++t) e5[t] = {0.f, 0.f, 0.f, 0.f};
    #pragma unroll
    for (int kc = 0; kc < 2; ++kc)
      #pragma unroll
      for (int nt = 0; nt < 5; ++nt) {
        int t16 = t016 + nt; t16 = t16 > 31 ? 31 : t16;
        short8 rb = *(const short8*)(RF + rhead + (size_t)(t16 * 2 + kc) * 512 + fchunk);
        e5[nt] = __builtin_amdgcn_mfma_f32_16x16x32_bf16(va[kc], rb, e5[nt], 0, 0, 0);
      }
    __builtin_amdgcn_s_setprio(0);

    // ---- rel-shift rotate within 16-lane groups ----
    float rot[5][4];
    #pragma unroll
    for (int q = 0; q < 4; ++q) {
      int src = (lane & 48) | ((15 - (g * 4 + q) + c15) & 15);
      #pragma unroll
      for (int nt = 0; nt < 5; ++nt)
        rot[nt][q] = __shfl(e5[nt][q], src, 64);
    }

    // ---- combine + causal mask ----
    float s[4][4];
    #pragma unroll
    for (int ct = 0; ct < 4; ++ct) {
      int jcol = j0 + ct * 16 + c15;
      #pragma unroll
      for (int q = 0; q < 4; ++q) {
        int r = g * 4 + q;
        int u = 15 - r + c15;
        float bd = (u >> 4) ? rot[ct + 1][q] : rot[ct][q];
        float sv = ac[ct][q] + bd;
        s[ct][q] = (jcol <= i0w + r) ? sv : -1e30f;
      }
    }

    // ---- online softmax ----
    float mnew[4], csc[4];
    #pragma unroll
    for (int q = 0; q < 4; ++q) {
      float mx = fmaxf(fmaxf(s[0][q], s[1][q]), fmaxf(s[2][q], s[3][q]));
      #pragma unroll
      for (int o = 8; o; o >>= 1) mx = fmaxf(mx, __shfl_xor(mx, o, 64));
      mnew[q] = fmaxf(m[q], mx);
      csc[q] = __expf(m[q] - mnew[q]);
      m[q] = mnew[q];
    }
    float rs[4] = {0.f, 0.f, 0.f, 0.f};
    float p[4][4];
    #pragma unroll
    for (int ct = 0; ct < 4; ++ct)
      #pragma unroll
      for (int q = 0; q < 4; ++q) {
        p[ct][q] = __expf(s[ct][q] - mnew[q]);
        rs[q] += p[ct][q];
      }
    #pragma unroll
    for (int q = 0; q < 4; ++q) {
      float t = rs[q];
      #pragma unroll
      for (int o = 8; o; o >>= 1) t += __shfl_xor(t, o, 64);
      l[q] = l[q] * csc[q] + t;
      #pragma unroll
      for (int ct = 0; ct < 4; ++ct) oacc[ct][q] *= csc[q];
    }

    // ---- P -> bf16 via per-wave LDS transpose (wave-local) ----
    #pragma unroll
    for (int ct = 0; ct < 4; ++ct)
      #pragma unroll
      for (int q = 0; q < 4; ++q)
        pw[(g * 4 + q) * 72 + ct * 16 + c15] = f2b(p[ct][q]);

    // ---- PV from staged VT ----
    __builtin_amdgcn_s_setprio(1);
    #pragma unroll
    for (int kc = 0; kc < 2; ++kc) {
      short8 pa = *(const short8*)&pw[c15 * 72 + kc * 32 + g * 8];
      #pragma unroll
      for (int nt = 0; nt < 4; ++nt) {
        short8 vb8 = *(const short8*)&lVT[buf][(nt * 2 + kc) * 512 + fchunk];
        oacc[nt] = __builtin_amdgcn_mfma_f32_16x16x32_bf16(pa, vb8, oacc[nt], 0, 0, 0);
      }
    }
    __builtin_amdgcn_s_setprio(0);

    // ---- phase switch: write q-tile A, reset for B ----
    if (s2 == x) {
      #pragma unroll
      for (int q = 0; q < 4; ++q) {
        float rl = 1.f / l[q];
        size_t ro = bh_off + (size_t)(i0w + g * 4 + q) * Ec;
        #pragma unroll
        for (int ct = 0; ct < 4; ++ct)
          out[ro + ct * 16 + c15] = f2b(oacc[ct][q] * rl);
      }
      i0w = qB * 64 + wave * 16;
      int i16g = b * 32 + (i0w >> 4);
      #pragma unroll
      for (int kc = 0; kc < 2; ++kc) {
        size_t off = qhead + ((size_t)(i16g * 2 + kc) * 64) * 8 + fchunk;
        qa[kc] = *(const short8*)(quF + off);
        va[kc] = *(const short8*)(qvF + off);
      }
      #pragma unroll
      for (int t = 0; t < 4; ++t) oacc[t] = {0.f, 0.f, 0.f, 0.f};
      #pragma unroll
      for (int q = 0; q < 4; ++q) { m[q] = -1e30f; l[q] = 0.f; }
    }

    asm volatile("s_waitcnt vmcnt(0)" ::: "memory");
    __syncthreads();
  }

  // ---- write q-tile B ----
  #pragma unroll
  for (int q = 0; q < 4; ++q) {
    float rl = 1.f / l[q];
    size_t ro = bh_off + (size_t)(i0w + g * 4 + q) * Ec;
    #pragma unroll
    for (int ct = 0; ct < 4; ++ct)
      out[ro + ct * 16 + c15] = f2b(oacc[ct][q] * rl);
  }
}

// ---------------------------------------------------------------------------
extern "C" void kernel_launch(void* const* d_in, const int* in_sizes, int n_in,
                              void* d_out, int out_size, void* d_ws, size_t ws_size,
                              hipStream_t stream) {
  (void)in_sizes; (void)n_in; (void)out_size; (void)ws_size;

  const float* query = (const float*)d_in[0];
  const float* key   = (const float*)d_in[1];
  const float* ln1_g = (const float*)d_in[4];
  const float* ln1_b = (const float*)d_in[5];
  const float* ln2_g = (const float*)d_in[6];
  const float* ln2_b = (const float*)d_in[7];
  const float* Wq = (const float*)d_in[8];   const float* bq = (const float*)d_in[9];
  const float* Wk = (const float*)d_in[10];  const float* bk = (const float*)d_in[11];
  const float* Wv = (const float*)d_in[12];  const float* bv_in = (const float*)d_in[13];
  const float* Wp = (const float*)d_in[14];
  const float* Wo = (const float*)d_in[15];  const float* bo = (const float*)d_in[16];
  const float* u_bias = (const float*)d_in[17];
  const float* v_bias = (const float*)d_in[18];
  const float* fc_W = (const float*)d_in[31]; const float* fc_b = (const float*)d_in[32];

  const size_t MB = 1ull << 20;
  char* ws = (char*)d_ws;
  u16* wb[18];
  for (int i = 0; i < 18; ++i) wb[i] = (u16*)(ws + (size_t)i * 2 * MB);
  u16*   normq16 = (u16*)(ws + 36 * MB);  // -> att16 -> rx16
  u16*   normk16 = (u16*)(ws + 44 * MB);  // -> Y16
  u16*   xq16    = (u16*)(ws + 52 * MB);  // -> ln2o16
  u16*   pos16   = (u16*)(ws + 60 * MB);
  u16*   rF16    = (u16*)(ws + 61 * MB);  // R fragment layout (512KB)
  u16*   quF16   = (u16*)(ws + 62 * MB);  // -> out116
  u16*   qvF16   = (u16*)(ws + 70 * MB);  // -> Ef16
  u16*   pk16    = (u16*)(ws + 78 * MB);  // \ -> tB f32 (16MB)
  u16*   pvt16   = (u16*)(ws + 86 * MB);  // /
  float* out1    = (float*)(ws + 94 * MB);// 16MB
  u16*   att16   = normq16;
  u16*   Y16     = normk16;
  u16*   rx16    = normq16;
  u16*   out116  = quF16;
  u16*   Ef16    = qvF16;
  u16*   ln2o16  = xq16;
  float* tB      = (float*)pk16;

  // --- weight conversion ---
  PtrBundle pb;
  const float* wsrc[18] = {Wq, Wk, Wv, Wp, Wo, fc_W,
                           (const float*)d_in[19], (const float*)d_in[20],
                           (const float*)d_in[21], (const float*)d_in[22],
                           (const float*)d_in[23], (const float*)d_in[24],
                           (const float*)d_in[25], (const float*)d_in[26],
                           (const float*)d_in[27], (const float*)d_in[28],
                           (const float*)d_in[29], (const float*)d_in[30]};
  for (int i = 0; i < 18; ++i) { pb.src[i] = wsrc[i]; pb.dst[i] = wb[i]; }
  cvtw_kernel<<<dim3(1024, 18), 256, 0, stream>>>(pb);

  // --- stage 1 (query LN also emits raw bf16 copy -> xq16) ---
  ln_kernel<<<4096, 256, 0, stream>>>(query, ln1_g, ln1_b, normq16, xq16);
  ln_kernel<<<4096, 256, 0, stream>>>(key,   ln1_g, ln1_b, normk16, nullptr);
  posenc_kernel<<<1024, 256, 0, stream>>>(pos16);

  GemmSeg z{}; GemmDesc d;

  // --- QKV fused (grid 32x24, TN=128): Q->frag(1/8), K->frag, V->VT-frag ---
  d.seg[0] = z; d.seg[0].A1 = normq16; d.seg[0].W1 = wb[0]; d.seg[0].bias = bq;
  d.seg[0].bu = u_bias; d.seg[0].bv = v_bias;
  d.seg[0].o16a = quF16; d.seg[0].o16b = qvF16; d.seg[0].epi = 1;
  d.seg[1] = z; d.seg[1].A1 = normk16; d.seg[1].W1 = wb[1]; d.seg[1].bias = bk;
  d.seg[1].o16a = pk16; d.seg[1].epi = 7;
  d.seg[2] = z; d.seg[2].A1 = normk16; d.seg[2].W1 = wb[2]; d.seg[2].bias = bv_in;
  d.seg[2].o16a = pvt16; d.seg[2].epi = 6;
  gemm_f<128><<<dim3(32, 24), 256, 0, stream>>>(d);

  // --- Wp (M=512, TN=64, grid 4x16) -> R fragment layout ---
  d.seg[0] = z; d.seg[0].A1 = pos16; d.seg[0].W1 = wb[3];
  d.seg[0].o16a = rF16; d.seg[0].epi = 8;
  gemm_f<64><<<dim3(4, 16), 256, 0, stream>>>(d);

  // --- attention (balanced pairing, grid 4x16x8) ---
  attn_mfma<<<dim3(4, 16, 8), 256, 0, stream>>>(quF16, qvF16, pk16, pvt16,
                                                rF16, att16);

  // --- Wo (TN=64, grid 32x16) ---
  d.seg[0] = z; d.seg[0].A1 = att16; d.seg[0].W1 = wb[4]; d.seg[0].bias = bo;
  d.seg[0].o16a = Y16; d.seg[0].epi = 0;
  gemm_f<64><<<dim3(32, 16), 256, 0, stream>>>(d);

  // --- gate1 r+z (dual-K, TN=128, grid 32x16) ---
  d.seg[0] = z; d.seg[0].A1 = Y16; d.seg[0].A2 = xq16;
  d.seg[0].W1 = wb[6]; d.seg[0].W2 = wb[7];
  d.seg[0].xF = query; d.seg[0].o16a = rx16; d.seg[0].epi = 3;
  d.seg[1] = z; d.seg[1].A1 = Y16; d.seg[1].A2 = xq16;
  d.seg[1].W1 = wb[8]; d.seg[1].W2 = wb[9];
  d.seg[1].oF = tB; d.seg[1].epi = 2;
  gemm_f<128><<<dim3(32, 16), 256, 0, stream>>>(d);

  // --- gate1 g + combine (dual-K, TN=64, grid 32x16) ---
  d.seg[0] = z; d.seg[0].A1 = Y16; d.seg[0].A2 = rx16;
  d.seg[0].W1 = wb[10]; d.seg[0].W2 = wb[11];
  d.seg[0].xF = query; d.seg[0].zF = tB;
  d.seg[0].oF = out1; d.seg[0].o16a = out116; d.seg[0].epi = 4;
  gemm_f<64><<<dim3(32, 16), 256, 0, stream>>>(d);

  // --- FFN ---
  ln_kernel<<<4096, 256, 0, stream>>>(out1, ln2_g, ln2_b, ln2o16, nullptr);
  d.seg[0] = z; d.seg[0].A1 = ln2o16; d.seg[0].W1 = wb[5]; d.seg[0].bias = fc_b;
  d.seg[0].o16a = Ef16; d.seg[0].epi = 5;
  gemm_f<64><<<dim3(32, 16), 256, 0, stream>>>(d);

  // --- gate2 r+z (dual-K, TN=128, grid 32x16) ---
  d.seg[0] = z; d.seg[0].A1 = Ef16; d.seg[0].A2 = out116;
  d.seg[0].W1 = wb[12]; d.seg[0].W2 = wb[13];
  d.seg[0].xF = out1; d.seg[0].o16a = rx16; d.seg[0].epi = 3;
  d.seg[1] = z; d.seg[1].A1 = Ef16; d.seg[1].A2 = out116;
  d.seg[1].W1 = wb[14]; d.seg[1].W2 = wb[15];
  d.seg[1].oF = tB; d.seg[1].epi = 2;
  gemm_f<128><<<dim3(32, 16), 256, 0, stream>>>(d);

  // --- gate2 g + final combine (dual-K, TN=64, grid 32x16) ---
  d.seg[0] = z; d.seg[0].A1 = Ef16; d.seg[0].A2 = rx16;
  d.seg[0].W1 = wb[16]; d.seg[0].W2 = wb[17];
  d.seg[0].xF = out1; d.seg[0].zF = tB;
  d.seg[0].oF = (float*)d_out; d.seg[0].epi = 4;
  gemm_f<64><<<dim3(32, 16), 256, 0, stream>>>(d);
}